// Round 5
// baseline (367.619 us; speedup 1.0000x reference)
//
#include <hip/hip_runtime.h>
#include <math.h>

#define NN 10000
#define EE 160000
#define MP 10112   // 79*128, padded node count
#define EPSBN 1e-5f

typedef __attribute__((ext_vector_type(8))) short short8;
typedef __attribute__((ext_vector_type(4))) short short4v;
typedef __attribute__((ext_vector_type(4))) float f32x4;

__device__ __forceinline__ short f2bf(float f) {
    union { float f; unsigned u; } v; v.f = f;
    unsigned r = v.u + 0x7FFF + ((v.u >> 16) & 1);
    return (short)(r >> 16);
}
__device__ __forceinline__ float bf2f(unsigned short u) {
    union { unsigned u; float f; } v; v.u = ((unsigned)u) << 16;
    return v.f;
}
__device__ __forceinline__ void gload16(const short* g, short* l) {
    __builtin_amdgcn_global_load_lds((const __attribute__((address_space(1))) void*)g,
                                     (__attribute__((address_space(3))) void*)l, 16, 0, 0);
}

// ---------------- CSR build ----------------

__global__ void count_kernel(const int* __restrict__ dst, int* __restrict__ deg, int E) {
    int e = blockIdx.x * blockDim.x + threadIdx.x;
    if (e < E) atomicAdd(&deg[dst[e]], 1);
}

__global__ __launch_bounds__(1024) void scan_kernel(const int* __restrict__ deg, int* __restrict__ off,
                                                    int* __restrict__ cursor, int n) {
    __shared__ int sm[1024];
    const int C = 10;
    int t = threadIdx.x;
    int base = t * C;
    int loc[C];
    int acc = 0;
#pragma unroll
    for (int i = 0; i < C; i++) {
        int idx = base + i;
        int v = (idx < n) ? deg[idx] : 0;
        loc[i] = acc;
        acc += v;
    }
    sm[t] = acc;
    __syncthreads();
    for (int d = 1; d < 1024; d <<= 1) {
        int v = (t >= d) ? sm[t - d] : 0;
        __syncthreads();
        sm[t] += v;
        __syncthreads();
    }
    int prefix = (t > 0) ? sm[t - 1] : 0;
#pragma unroll
    for (int i = 0; i < C; i++) {
        int idx = base + i;
        if (idx < n) {
            int o = prefix + loc[i];
            off[idx] = o;
            cursor[idx] = o;
        }
    }
    if (t == 1023) off[n] = sm[1023];
}

__global__ void fill_kernel(const int* __restrict__ src, const int* __restrict__ dst,
                            const float* __restrict__ ew, int* __restrict__ cursor,
                            int* __restrict__ psrc, float* __restrict__ pew, int E) {
    int e = blockIdx.x * blockDim.x + threadIdx.x;
    if (e < E) {
        int d = dst[e];
        int slot = atomicAdd(&cursor[d], 1);
        psrc[slot] = src[e];
        pew[slot] = ew[e];
    }
}

// ---------------- weights convert (all 3 layers in one kernel) ----------------

__global__ void conv_w_all(const float* __restrict__ w1r, const float* __restrict__ w1o,
                           const float* __restrict__ w2r, const float* __restrict__ w2o,
                           const float* __restrict__ w3r, const float* __restrict__ w3o,
                           short* __restrict__ B1, short* __restrict__ B2, short* __restrict__ B3) {
    int j = blockIdx.x;
    const float *Wr, *Wo;
    short* Bt;
    int K, Kp, fo, row;
    if (j < 512)      { row = j;       Wr = w1r; Wo = w1o; Bt = B1; K = 517; Kp = 576; fo = 256; }
    else if (j < 768) { row = j - 512; Wr = w2r; Wo = w2o; Bt = B2; K = 256; Kp = 256; fo = 128; }
    else              { row = j - 768; Wr = w3r; Wo = w3o; Bt = B3; K = 128; Kp = 128; fo = 64; }
    const float* W = (row < fo) ? Wr : Wo;
    int col = (row < fo) ? row : row - fo;
    for (int k = threadIdx.x; k < Kp; k += 256) {
        short v = 0;
        if (k < K) v = f2bf(W[(size_t)k * fo + col]);
        Bt[(size_t)row * Kp + k] = v;
    }
}

// ---------------- MFMA GEMM with fused A-transform ----------------
// MODE 0: A = x f32 [NN,K], convert only (guarded)
// MODE 1: A = hio f32 [MP,K], BN(from sums)+ReLU, convert
// Tile 128x128, BK=64. Writes Yrel bf16 [MP,fo] and Hroot f32 [MP,fo] (+brel).

template <int MODE>
__global__ __launch_bounds__(256) void mfma_gemm(const float* __restrict__ A,
                                                 const short* __restrict__ Bt,
                                                 short* __restrict__ Yrel,
                                                 float* __restrict__ Hroot,
                                                 const float* __restrict__ brel,
                                                 const float* __restrict__ ssum,
                                                 const float* __restrict__ ssumsq,
                                                 const float* __restrict__ bng,
                                                 const float* __restrict__ bnb,
                                                 int K, int Kp, int fo) {
    __shared__ short Als[128 * 64];
    __shared__ short Bls[128 * 64];
    __shared__ float scs[256], shs[256];

    int m0 = blockIdx.x * 128;
    int n0 = blockIdx.y * 128;
    int t = threadIdx.x;
    int lane = t & 63;
    int wid = t >> 6;

    if (MODE == 1) {
        for (int f = t; f < K; f += 256) {
            float mean = ssum[f] / (float)NN;
            float var = ssumsq[f] / (float)NN - mean * mean;
            var = fmaxf(var, 0.f);
            float sc = bng[f] * rsqrtf(var + EPSBN);
            scs[f] = sc;
            shs[f] = bnb[f] - mean * sc;
        }
        __syncthreads();
    }

    f32x4 acc[2][8];
#pragma unroll
    for (int i = 0; i < 2; i++)
#pragma unroll
        for (int j = 0; j < 8; j++) acc[i][j] = (f32x4){0.f, 0.f, 0.f, 0.f};

    for (int k0 = 0; k0 < Kp; k0 += 64) {
#pragma unroll
        for (int i = 0; i < 4; i++) {
            int idx = i * 256 + t;
            int row = idx >> 3;
            int pc = idx & 7;
            gload16(Bt + (size_t)(n0 + row) * Kp + k0 + ((pc ^ (row & 7)) << 3), &Bls[idx << 3]);
        }
#pragma unroll
        for (int i = 0; i < 8; i++) {
            int idx = i * 256 + t;
            int row = idx >> 4;
            int fc = idx & 15;
            int g = m0 + row;
            int kb = k0 + (fc << 2);
            float v[4];
            if (MODE == 0) {
                const float* ap = A + (size_t)g * K + kb;
                bool gr = (g < NN);
#pragma unroll
                for (int j = 0; j < 4; j++) v[j] = (gr && kb + j < K) ? ap[j] : 0.f;
            } else {
                f32x4 x4 = *(const f32x4*)(A + (size_t)g * K + kb);
#pragma unroll
                for (int j = 0; j < 4; j++) v[j] = fmaxf(0.f, x4[j] * scs[kb + j] + shs[kb + j]);
            }
            short4v s;
#pragma unroll
            for (int j = 0; j < 4; j++) s[j] = f2bf(v[j]);
            *(short4v*)&Als[row * 64 + (((fc >> 1) ^ (row & 7)) << 3) + ((fc & 1) << 2)] = s;
        }
        __syncthreads();
#pragma unroll
        for (int kk = 0; kk < 2; kk++) {
            short8 af[2], bfr[8];
#pragma unroll
            for (int mi = 0; mi < 2; mi++) {
                int row = wid * 32 + mi * 16 + (lane & 15);
                int cc = kk * 4 + (lane >> 4);
                af[mi] = *(const short8*)&Als[(row * 8 + (cc ^ (row & 7))) * 8];
            }
#pragma unroll
            for (int ni = 0; ni < 8; ni++) {
                int row = ni * 16 + (lane & 15);
                int cc = kk * 4 + (lane >> 4);
                bfr[ni] = *(const short8*)&Bls[(row * 8 + (cc ^ (row & 7))) * 8];
            }
#pragma unroll
            for (int mi = 0; mi < 2; mi++)
#pragma unroll
                for (int ni = 0; ni < 8; ni++)
                    acc[mi][ni] = __builtin_amdgcn_mfma_f32_16x16x32_bf16(af[mi], bfr[ni], acc[mi][ni], 0, 0, 0);
        }
        __syncthreads();
    }

#pragma unroll
    for (int mi = 0; mi < 2; mi++) {
#pragma unroll
        for (int ni = 0; ni < 8; ni++) {
            int gn = n0 + ni * 16 + (lane & 15);
            int row0 = m0 + wid * 32 + mi * 16 + (lane >> 4) * 4;
            f32x4 v = acc[mi][ni];
            if (gn < fo) {
#pragma unroll
                for (int r = 0; r < 4; r++) Yrel[(size_t)(row0 + r) * fo + gn] = f2bf(v[r]);
            } else {
                float bb = brel[gn - fo];
#pragma unroll
                for (int r = 0; r < 4; r++) Hroot[(size_t)(row0 + r) * fo + (gn - fo)] = v[r] + bb;
            }
        }
    }
}

// ---------------- aggregation + per-block stats PARTIALS (no global atomics) ----------------
// CHUNK == fo. G = CHUNK/2 threads per node, NPB = 256/G nodes per block.
// Block writes its stats partial vector to pSum/pSq[blockIdx.x * CHUNK + f].

template <int CHUNK>
__global__ __launch_bounds__(256) void agg_part(const short* __restrict__ Yrel,
                                                float* __restrict__ hio,
                                                const int* __restrict__ off,
                                                const int* __restrict__ psrc,
                                                const float* __restrict__ pew,
                                                float* __restrict__ pSum,
                                                float* __restrict__ pSq) {
    const int G = CHUNK / 2;
    const int NPB = 256 / G;
    __shared__ float sm[2 * CHUNK];
    int t = threadIdx.x;
    int g = t / G;
    int tf = t % G;
    int f = tf * 2;
    int n = blockIdx.x * NPB + g;

    float v0 = 0.f, v1 = 0.f;
    bool valid = (n < NN);
    if (valid) {
        float a0 = 0.f, a1 = 0.f;
        int e0 = off[n], e1 = off[n + 1];
        int e = e0;
        for (; e + 1 < e1; e += 2) {
            int s0i = psrc[e], s1i = psrc[e + 1];
            float w0 = pew[e], w1 = pew[e + 1];
            unsigned p0 = *(const unsigned*)(Yrel + (size_t)s0i * CHUNK + f);
            unsigned p1 = *(const unsigned*)(Yrel + (size_t)s1i * CHUNK + f);
            a0 += w0 * bf2f((unsigned short)(p0 & 0xffff));
            a1 += w0 * bf2f((unsigned short)(p0 >> 16));
            a0 += w1 * bf2f((unsigned short)(p1 & 0xffff));
            a1 += w1 * bf2f((unsigned short)(p1 >> 16));
        }
        if (e < e1) {
            int s0i = psrc[e];
            float w0 = pew[e];
            unsigned p0 = *(const unsigned*)(Yrel + (size_t)s0i * CHUNK + f);
            a0 += w0 * bf2f((unsigned short)(p0 & 0xffff));
            a1 += w0 * bf2f((unsigned short)(p0 >> 16));
        }
        size_t o = (size_t)n * CHUNK + f;
        v0 = hio[o] + a0;
        v1 = hio[o + 1] + a1;
        hio[o] = v0;
        hio[o + 1] = v1;
    }

    if (t < 2 * CHUNK) sm[t] = 0.f;
    __syncthreads();
    if (valid) {
        atomicAdd(&sm[f], v0);
        atomicAdd(&sm[f + 1], v1);
        atomicAdd(&sm[CHUNK + f], v0 * v0);
        atomicAdd(&sm[CHUNK + f + 1], v1 * v1);
    }
    __syncthreads();
    if (t < CHUNK) {
        size_t o = (size_t)blockIdx.x * CHUNK + t;
        pSum[o] = sm[t];
        pSq[o] = sm[CHUNK + t];
    }
}

// ---------------- partial reduce: ssum[f] = sum_r pSum[r][f] (16-deep atomics) ----------------

template <int F>
__global__ void reduce_part(const float* __restrict__ pSum, const float* __restrict__ pSq,
                            float* __restrict__ ssum, float* __restrict__ ssumsq, int GX) {
    int f = threadIdx.x;
    int nb = gridDim.x;
    int per = (GX + nb - 1) / nb;
    int r0 = blockIdx.x * per;
    int r1 = r0 + per;
    if (r1 > GX) r1 = GX;
    float s = 0.f, q = 0.f;
    for (int r = r0; r < r1; r++) {
        s += pSum[(size_t)r * F + f];
        q += pSq[(size_t)r * F + f];
    }
    atomicAdd(&ssum[f], s);
    atomicAdd(&ssumsq[f], q);
}

// ---------------- head: BN3 + ReLU + dot(wlin) + log_sigmoid ----------------

__global__ void head_kernel(const float* __restrict__ hio,
                            const float* __restrict__ ssum, const float* __restrict__ ssumsq,
                            const float* __restrict__ g3, const float* __restrict__ b3,
                            const float* __restrict__ wlin, const float* __restrict__ blin,
                            float* __restrict__ tmp) {
    int lane = threadIdx.x & 63;
    int wv = threadIdx.x >> 6;
    int n = blockIdx.x * 4 + wv;
    float mean = ssum[lane] / (float)NN;
    float var = ssumsq[lane] / (float)NN - mean * mean;
    var = fmaxf(var, 0.f);
    float sc = g3[lane] * rsqrtf(var + EPSBN);
    float sh = b3[lane] - mean * sc;
    float v = fmaxf(0.f, hio[(size_t)n * 64 + lane] * sc + sh);
    float p = v * wlin[lane];
#pragma unroll
    for (int o = 32; o > 0; o >>= 1) p += __shfl_down(p, o, 64);
    if (lane == 0) {
        float x = p + blin[0];
        float ls = (x >= 0.f) ? (-log1pf(expf(-x))) : (x - log1pf(expf(x)));
        tmp[n] = ls;
    }
}

// ---------------- logsumexp + final subtract (one block) ----------------

__global__ __launch_bounds__(1024) void lse_final(const float* __restrict__ tmp, float* __restrict__ out) {
    __shared__ float sm[1024];
    int t = threadIdx.x;
    float m = -INFINITY;
    for (int i = t; i < NN; i += 1024) m = fmaxf(m, tmp[i]);
    sm[t] = m;
    __syncthreads();
    for (int s = 512; s > 0; s >>= 1) {
        if (t < s) sm[t] = fmaxf(sm[t], sm[t + s]);
        __syncthreads();
    }
    float M = sm[0];
    __syncthreads();
    float acc = 0.f;
    for (int i = t; i < NN; i += 1024) acc += expf(tmp[i] - M);
    sm[t] = acc;
    __syncthreads();
    for (int s = 512; s > 0; s >>= 1) {
        if (t < s) sm[t] += sm[t + s];
        __syncthreads();
    }
    float L = M + logf(sm[0]);
    for (int i = t; i < NN; i += 1024) out[i] = tmp[i] - L;
}

// ---------------- launch ----------------

extern "C" void kernel_launch(void* const* d_in, const int* in_sizes, int n_in,
                              void* d_out, int out_size, void* d_ws, size_t ws_size,
                              hipStream_t stream) {
    const float* x  = (const float*)d_in[0];
    const int* ei   = (const int*)d_in[1];
    const float* ew = (const float*)d_in[2];
    const int* src = ei;
    const int* dst = ei + EE;

    const float* wrel[3]  = { (const float*)d_in[3],  (const float*)d_in[8],  (const float*)d_in[13] };
    const float* brel[3]  = { (const float*)d_in[4],  (const float*)d_in[9],  (const float*)d_in[14] };
    const float* wroot[3] = { (const float*)d_in[5],  (const float*)d_in[10], (const float*)d_in[15] };
    const float* bng[3]   = { (const float*)d_in[6],  (const float*)d_in[11], (const float*)d_in[16] };
    const float* bnb[3]   = { (const float*)d_in[7],  (const float*)d_in[12], (const float*)d_in[17] };
    const float* wlin = (const float*)d_in[18];
    const float* blin = (const float*)d_in[19];
    float* out = (float*)d_out;

    char* p = (char*)d_ws;
    auto alloc = [&](size_t bytes) { char* r = p; p += (bytes + 255) & ~(size_t)255; return r; };

    int*   deg     = (int*)alloc(NN * 4);           // memset region start
    float* ssumAll = (float*)alloc(1536 * 4);       // 3 layers x (sum[256]+sumsq[256])
    int*   off     = (int*)alloc((NN + 4) * 4);
    int*   cursor  = (int*)alloc(NN * 4);
    int*   psrc    = (int*)alloc(EE * 4);
    float* pew     = (float*)alloc(EE * 4);
    short* B1t     = (short*)alloc((size_t)512 * 576 * 2);
    short* B2t     = (short*)alloc((size_t)256 * 256 * 2);
    short* B3t     = (short*)alloc((size_t)128 * 128 * 2);
    short* Yrel    = (short*)alloc((size_t)MP * 256 * 2);
    float* hA      = (float*)alloc((size_t)MP * 256 * 4);
    float* hB      = (float*)alloc((size_t)MP * 128 * 4);
    float* hC      = (float*)alloc((size_t)MP * 64 * 4);
    float* tmp     = (float*)alloc(NN * 4);
    float* pSum    = (float*)alloc((size_t)5000 * 256 * 4);
    float* pSq     = (float*)alloc((size_t)5000 * 256 * 4);

    float* ss[3]  = { ssumAll,       ssumAll + 512,  ssumAll + 1024 };
    float* sq[3]  = { ssumAll + 256, ssumAll + 768,  ssumAll + 1280 };

    hipMemsetAsync(deg, 0, (size_t)((char*)(ssumAll + 1536) - (char*)deg), stream);

    count_kernel<<<(EE + 255) / 256, 256, 0, stream>>>(dst, deg, EE);
    scan_kernel<<<1, 1024, 0, stream>>>(deg, off, cursor, NN);
    fill_kernel<<<(EE + 255) / 256, 256, 0, stream>>>(src, dst, ew, cursor, psrc, pew, EE);
    conv_w_all<<<896, 256, 0, stream>>>(wrel[0], wroot[0], wrel[1], wroot[1], wrel[2], wroot[2],
                                        B1t, B2t, B3t);

    // layer 1 (fo=256): 2 nodes/block, 5000 blocks
    mfma_gemm<0><<<dim3(MP / 128, 4), 256, 0, stream>>>(x, B1t, Yrel, hA, brel[0],
                                                        nullptr, nullptr, nullptr, nullptr, 517, 576, 256);
    agg_part<256><<<5000, 256, 0, stream>>>(Yrel, hA, off, psrc, pew, pSum, pSq);
    reduce_part<256><<<16, 256, 0, stream>>>(pSum, pSq, ss[0], sq[0], 5000);

    // layer 2 (fo=128): 4 nodes/block, 2500 blocks
    mfma_gemm<1><<<dim3(MP / 128, 2), 256, 0, stream>>>(hA, B2t, Yrel, hB, brel[1],
                                                        ss[0], sq[0], bng[0], bnb[0], 256, 256, 128);
    agg_part<128><<<2500, 256, 0, stream>>>(Yrel, hB, off, psrc, pew, pSum, pSq);
    reduce_part<128><<<16, 128, 0, stream>>>(pSum, pSq, ss[1], sq[1], 2500);

    // layer 3 (fo=64): 8 nodes/block, 1250 blocks
    mfma_gemm<1><<<dim3(MP / 128, 1), 256, 0, stream>>>(hB, B3t, Yrel, hC, brel[2],
                                                        ss[1], sq[1], bng[1], bnb[1], 128, 128, 64);
    agg_part<64><<<1250, 256, 0, stream>>>(Yrel, hC, off, psrc, pew, pSum, pSq);
    reduce_part<64><<<16, 64, 0, stream>>>(pSum, pSq, ss[2], sq[2], 1250);

    head_kernel<<<2500, 256, 0, stream>>>(hC, ss[2], sq[2], bng[2], bnb[2], wlin, blin, tmp);
    lse_final<<<1, 1024, 0, stream>>>(tmp, out);
}

// Round 6
// 250.674 us; speedup vs baseline: 1.4665x; 1.4665x over previous
//
#include <hip/hip_runtime.h>
#include <math.h>

#define NN 10000
#define EE 160000
#define MP 10112   // 79*128, padded node count
#define EPSBN 1e-5f

typedef __attribute__((ext_vector_type(8))) short short8;
typedef __attribute__((ext_vector_type(4))) short short4v;
typedef __attribute__((ext_vector_type(4))) float f32x4;

__device__ __forceinline__ short f2bf(float f) {
    union { float f; unsigned u; } v; v.f = f;
    unsigned r = v.u + 0x7FFF + ((v.u >> 16) & 1);
    return (short)(r >> 16);
}
__device__ __forceinline__ float bf2f(unsigned short u) {
    union { unsigned u; float f; } v; v.u = ((unsigned)u) << 16;
    return v.f;
}
__device__ __forceinline__ void gload16(const short* g, short* l) {
    __builtin_amdgcn_global_load_lds((const __attribute__((address_space(1))) void*)g,
                                     (__attribute__((address_space(3))) void*)l, 16, 0, 0);
}

// ---------------- CSR build ----------------

__global__ void count_kernel(const int* __restrict__ dst, int* __restrict__ deg, int E) {
    int e = blockIdx.x * blockDim.x + threadIdx.x;
    if (e < E) atomicAdd(&deg[dst[e]], 1);
}

__global__ __launch_bounds__(1024) void scan_kernel(const int* __restrict__ deg, int* __restrict__ off,
                                                    int* __restrict__ cursor, int n) {
    __shared__ int sm[1024];
    const int C = 10;
    int t = threadIdx.x;
    int base = t * C;
    int loc[C];
    int acc = 0;
#pragma unroll
    for (int i = 0; i < C; i++) {
        int idx = base + i;
        int v = (idx < n) ? deg[idx] : 0;
        loc[i] = acc;
        acc += v;
    }
    sm[t] = acc;
    __syncthreads();
    for (int d = 1; d < 1024; d <<= 1) {
        int v = (t >= d) ? sm[t - d] : 0;
        __syncthreads();
        sm[t] += v;
        __syncthreads();
    }
    int prefix = (t > 0) ? sm[t - 1] : 0;
#pragma unroll
    for (int i = 0; i < C; i++) {
        int idx = base + i;
        if (idx < n) {
            int o = prefix + loc[i];
            off[idx] = o;
            cursor[idx] = o;
        }
    }
    if (t == 1023) off[n] = sm[1023];
}

__global__ void fill_kernel(const int* __restrict__ src, const int* __restrict__ dst,
                            const float* __restrict__ ew, int* __restrict__ cursor,
                            int* __restrict__ psrc, float* __restrict__ pew, int E) {
    int e = blockIdx.x * blockDim.x + threadIdx.x;
    if (e < E) {
        int d = dst[e];
        int slot = atomicAdd(&cursor[d], 1);
        psrc[slot] = src[e];
        pew[slot] = ew[e];
    }
}

// ---------------- weights convert (all 3 layers in one kernel) ----------------

__global__ void conv_w_all(const float* __restrict__ w1r, const float* __restrict__ w1o,
                           const float* __restrict__ w2r, const float* __restrict__ w2o,
                           const float* __restrict__ w3r, const float* __restrict__ w3o,
                           short* __restrict__ B1, short* __restrict__ B2, short* __restrict__ B3) {
    int j = blockIdx.x;
    const float *Wr, *Wo;
    short* Bt;
    int K, Kp, fo, row;
    if (j < 512)      { row = j;       Wr = w1r; Wo = w1o; Bt = B1; K = 517; Kp = 576; fo = 256; }
    else if (j < 768) { row = j - 512; Wr = w2r; Wo = w2o; Bt = B2; K = 256; Kp = 256; fo = 128; }
    else              { row = j - 768; Wr = w3r; Wo = w3o; Bt = B3; K = 128; Kp = 128; fo = 64; }
    const float* W = (row < fo) ? Wr : Wo;
    int col = (row < fo) ? row : row - fo;
    for (int k = threadIdx.x; k < Kp; k += 256) {
        short v = 0;
        if (k < K) v = f2bf(W[(size_t)k * fo + col]);
        Bt[(size_t)row * Kp + k] = v;
    }
}

// ---------------- MFMA GEMM with fused A-transform ----------------
// MODE 0: A = x f32 [NN,K], convert only (guarded)
// MODE 1: A = hio f32 [MP,K], BN(from sums)+ReLU, convert
// Tile 128x128, BK=64. Writes Yrel bf16 [MP,fo] and Hroot f32 [MP,fo] (+brel).

template <int MODE>
__global__ __launch_bounds__(256) void mfma_gemm(const float* __restrict__ A,
                                                 const short* __restrict__ Bt,
                                                 short* __restrict__ Yrel,
                                                 float* __restrict__ Hroot,
                                                 const float* __restrict__ brel,
                                                 const float* __restrict__ ssum,
                                                 const float* __restrict__ ssumsq,
                                                 const float* __restrict__ bng,
                                                 const float* __restrict__ bnb,
                                                 int K, int Kp, int fo) {
    __shared__ short Als[128 * 64];
    __shared__ short Bls[128 * 64];
    __shared__ float scs[256], shs[256];

    int m0 = blockIdx.x * 128;
    int n0 = blockIdx.y * 128;
    int t = threadIdx.x;
    int lane = t & 63;
    int wid = t >> 6;

    if (MODE == 1) {
        for (int f = t; f < K; f += 256) {
            float mean = ssum[f] / (float)NN;
            float var = ssumsq[f] / (float)NN - mean * mean;
            var = fmaxf(var, 0.f);
            float sc = bng[f] * rsqrtf(var + EPSBN);
            scs[f] = sc;
            shs[f] = bnb[f] - mean * sc;
        }
        __syncthreads();
    }

    f32x4 acc[2][8];
#pragma unroll
    for (int i = 0; i < 2; i++)
#pragma unroll
        for (int j = 0; j < 8; j++) acc[i][j] = (f32x4){0.f, 0.f, 0.f, 0.f};

    for (int k0 = 0; k0 < Kp; k0 += 64) {
#pragma unroll
        for (int i = 0; i < 4; i++) {
            int idx = i * 256 + t;
            int row = idx >> 3;
            int pc = idx & 7;
            gload16(Bt + (size_t)(n0 + row) * Kp + k0 + ((pc ^ (row & 7)) << 3), &Bls[idx << 3]);
        }
#pragma unroll
        for (int i = 0; i < 8; i++) {
            int idx = i * 256 + t;
            int row = idx >> 4;
            int fc = idx & 15;
            int g = m0 + row;
            int kb = k0 + (fc << 2);
            float v[4];
            if (MODE == 0) {
                const float* ap = A + (size_t)g * K + kb;
                bool gr = (g < NN);
#pragma unroll
                for (int j = 0; j < 4; j++) v[j] = (gr && kb + j < K) ? ap[j] : 0.f;
            } else {
                f32x4 x4 = *(const f32x4*)(A + (size_t)g * K + kb);
#pragma unroll
                for (int j = 0; j < 4; j++) v[j] = fmaxf(0.f, x4[j] * scs[kb + j] + shs[kb + j]);
            }
            short4v s;
#pragma unroll
            for (int j = 0; j < 4; j++) s[j] = f2bf(v[j]);
            *(short4v*)&Als[row * 64 + (((fc >> 1) ^ (row & 7)) << 3) + ((fc & 1) << 2)] = s;
        }
        __syncthreads();
#pragma unroll
        for (int kk = 0; kk < 2; kk++) {
            short8 af[2], bfr[8];
#pragma unroll
            for (int mi = 0; mi < 2; mi++) {
                int row = wid * 32 + mi * 16 + (lane & 15);
                int cc = kk * 4 + (lane >> 4);
                af[mi] = *(const short8*)&Als[(row * 8 + (cc ^ (row & 7))) * 8];
            }
#pragma unroll
            for (int ni = 0; ni < 8; ni++) {
                int row = ni * 16 + (lane & 15);
                int cc = kk * 4 + (lane >> 4);
                bfr[ni] = *(const short8*)&Bls[(row * 8 + (cc ^ (row & 7))) * 8];
            }
#pragma unroll
            for (int mi = 0; mi < 2; mi++)
#pragma unroll
                for (int ni = 0; ni < 8; ni++)
                    acc[mi][ni] = __builtin_amdgcn_mfma_f32_16x16x32_bf16(af[mi], bfr[ni], acc[mi][ni], 0, 0, 0);
        }
        __syncthreads();
    }

#pragma unroll
    for (int mi = 0; mi < 2; mi++) {
#pragma unroll
        for (int ni = 0; ni < 8; ni++) {
            int gn = n0 + ni * 16 + (lane & 15);
            int row0 = m0 + wid * 32 + mi * 16 + (lane >> 4) * 4;
            f32x4 v = acc[mi][ni];
            if (gn < fo) {
#pragma unroll
                for (int r = 0; r < 4; r++) Yrel[(size_t)(row0 + r) * fo + gn] = f2bf(v[r]);
            } else {
                float bb = brel[gn - fo];
#pragma unroll
                for (int r = 0; r < 4; r++) Hroot[(size_t)(row0 + r) * fo + (gn - fo)] = v[r] + bb;
            }
        }
    }
}

// ---------------- pure aggregation (no stats): hio[n,f] += sum_e w*Yrel[src,f] ----------------

template <int FO>
__global__ __launch_bounds__(256) void agg_kernel(const short* __restrict__ Yrel,
                                                  float* __restrict__ hio,
                                                  const int* __restrict__ off,
                                                  const int* __restrict__ psrc,
                                                  const float* __restrict__ pew) {
    const int G = FO / 2;
    const int NPB = 256 / G;
    int t = threadIdx.x;
    int g = t / G;
    int tf = t % G;
    int f = tf * 2;
    int n = blockIdx.x * NPB + g;
    if (n >= NN) return;

    float a0 = 0.f, a1 = 0.f;
    int e0 = off[n], e1 = off[n + 1];
    int e = e0;
    for (; e + 1 < e1; e += 2) {
        int s0i = psrc[e], s1i = psrc[e + 1];
        float w0 = pew[e], w1 = pew[e + 1];
        unsigned p0 = *(const unsigned*)(Yrel + (size_t)s0i * FO + f);
        unsigned p1 = *(const unsigned*)(Yrel + (size_t)s1i * FO + f);
        a0 += w0 * bf2f((unsigned short)(p0 & 0xffff));
        a1 += w0 * bf2f((unsigned short)(p0 >> 16));
        a0 += w1 * bf2f((unsigned short)(p1 & 0xffff));
        a1 += w1 * bf2f((unsigned short)(p1 >> 16));
    }
    if (e < e1) {
        int s0i = psrc[e];
        float w0 = pew[e];
        unsigned p0 = *(const unsigned*)(Yrel + (size_t)s0i * FO + f);
        a0 += w0 * bf2f((unsigned short)(p0 & 0xffff));
        a1 += w0 * bf2f((unsigned short)(p0 >> 16));
    }
    size_t o = (size_t)n * FO + f;
    hio[o]     += a0;
    hio[o + 1] += a1;
}

// ---------------- BN stats: separate well-parallelized pass over hio ----------------
// 64 blocks x 256 threads; LANES=256/FO row-lanes; LDS reduce; atomic depth 64.

template <int FO>
__global__ __launch_bounds__(256) void stats_kernel(const float* __restrict__ hio,
                                                    float* __restrict__ ssum,
                                                    float* __restrict__ ssumsq) {
    const int LANES = 256 / FO;
    const int RPB = (NN + 63) / 64;   // 157
    __shared__ float sms[256], smq[256];
    int t = threadIdx.x;
    int f = t % FO;
    int rl = t / FO;
    int r0 = blockIdx.x * RPB;
    int r1 = r0 + RPB;
    if (r1 > NN) r1 = NN;
    float s = 0.f, q = 0.f;
    for (int r = r0 + rl; r < r1; r += LANES) {
        float v = hio[(size_t)r * FO + f];
        s += v;
        q += v * v;
    }
    if (LANES > 1) {
        sms[t] = s;
        smq[t] = q;
        __syncthreads();
        if (rl == 0) {
#pragma unroll
            for (int l = 1; l < LANES; l++) {
                s += sms[l * FO + f];
                q += smq[l * FO + f];
            }
        }
    }
    if (rl == 0) {
        atomicAdd(&ssum[f], s);
        atomicAdd(&ssumsq[f], q);
    }
}

// ---------------- head: BN3 + ReLU + dot(wlin) + log_sigmoid ----------------

__global__ void head_kernel(const float* __restrict__ hio,
                            const float* __restrict__ ssum, const float* __restrict__ ssumsq,
                            const float* __restrict__ g3, const float* __restrict__ b3,
                            const float* __restrict__ wlin, const float* __restrict__ blin,
                            float* __restrict__ tmp) {
    int lane = threadIdx.x & 63;
    int wv = threadIdx.x >> 6;
    int n = blockIdx.x * 4 + wv;
    float mean = ssum[lane] / (float)NN;
    float var = ssumsq[lane] / (float)NN - mean * mean;
    var = fmaxf(var, 0.f);
    float sc = g3[lane] * rsqrtf(var + EPSBN);
    float sh = b3[lane] - mean * sc;
    float v = fmaxf(0.f, hio[(size_t)n * 64 + lane] * sc + sh);
    float p = v * wlin[lane];
#pragma unroll
    for (int o = 32; o > 0; o >>= 1) p += __shfl_down(p, o, 64);
    if (lane == 0) {
        float x = p + blin[0];
        float ls = (x >= 0.f) ? (-log1pf(expf(-x))) : (x - log1pf(expf(x)));
        tmp[n] = ls;
    }
}

// ---------------- logsumexp + final subtract (one block) ----------------

__global__ __launch_bounds__(1024) void lse_final(const float* __restrict__ tmp, float* __restrict__ out) {
    __shared__ float sm[1024];
    int t = threadIdx.x;
    float m = -INFINITY;
    for (int i = t; i < NN; i += 1024) m = fmaxf(m, tmp[i]);
    sm[t] = m;
    __syncthreads();
    for (int s = 512; s > 0; s >>= 1) {
        if (t < s) sm[t] = fmaxf(sm[t], sm[t + s]);
        __syncthreads();
    }
    float M = sm[0];
    __syncthreads();
    float acc = 0.f;
    for (int i = t; i < NN; i += 1024) acc += expf(tmp[i] - M);
    sm[t] = acc;
    __syncthreads();
    for (int s = 512; s > 0; s >>= 1) {
        if (t < s) sm[t] += sm[t + s];
        __syncthreads();
    }
    float L = M + logf(sm[0]);
    for (int i = t; i < NN; i += 1024) out[i] = tmp[i] - L;
}

// ---------------- launch ----------------

extern "C" void kernel_launch(void* const* d_in, const int* in_sizes, int n_in,
                              void* d_out, int out_size, void* d_ws, size_t ws_size,
                              hipStream_t stream) {
    const float* x  = (const float*)d_in[0];
    const int* ei   = (const int*)d_in[1];
    const float* ew = (const float*)d_in[2];
    const int* src = ei;
    const int* dst = ei + EE;

    const float* wrel[3]  = { (const float*)d_in[3],  (const float*)d_in[8],  (const float*)d_in[13] };
    const float* brel[3]  = { (const float*)d_in[4],  (const float*)d_in[9],  (const float*)d_in[14] };
    const float* wroot[3] = { (const float*)d_in[5],  (const float*)d_in[10], (const float*)d_in[15] };
    const float* bng[3]   = { (const float*)d_in[6],  (const float*)d_in[11], (const float*)d_in[16] };
    const float* bnb[3]   = { (const float*)d_in[7],  (const float*)d_in[12], (const float*)d_in[17] };
    const float* wlin = (const float*)d_in[18];
    const float* blin = (const float*)d_in[19];
    float* out = (float*)d_out;

    char* p = (char*)d_ws;
    auto alloc = [&](size_t bytes) { char* r = p; p += (bytes + 255) & ~(size_t)255; return r; };

    int*   deg     = (int*)alloc(NN * 4);           // memset region start
    float* ssumAll = (float*)alloc(1536 * 4);       // 3 layers x (sum[256]+sumsq[256])
    int*   off     = (int*)alloc((NN + 4) * 4);
    int*   cursor  = (int*)alloc(NN * 4);
    int*   psrc    = (int*)alloc(EE * 4);
    float* pew     = (float*)alloc(EE * 4);
    short* B1t     = (short*)alloc((size_t)512 * 576 * 2);
    short* B2t     = (short*)alloc((size_t)256 * 256 * 2);
    short* B3t     = (short*)alloc((size_t)128 * 128 * 2);
    short* Yrel    = (short*)alloc((size_t)MP * 256 * 2);
    float* hA      = (float*)alloc((size_t)MP * 256 * 4);
    float* hB      = (float*)alloc((size_t)MP * 128 * 4);
    float* hC      = (float*)alloc((size_t)MP * 64 * 4);
    float* tmp     = (float*)alloc(NN * 4);

    float* ss[3]  = { ssumAll,       ssumAll + 512,  ssumAll + 1024 };
    float* sq[3]  = { ssumAll + 256, ssumAll + 768,  ssumAll + 1280 };

    hipMemsetAsync(deg, 0, (size_t)((char*)(ssumAll + 1536) - (char*)deg), stream);

    count_kernel<<<(EE + 255) / 256, 256, 0, stream>>>(dst, deg, EE);
    scan_kernel<<<1, 1024, 0, stream>>>(deg, off, cursor, NN);
    fill_kernel<<<(EE + 255) / 256, 256, 0, stream>>>(src, dst, ew, cursor, psrc, pew, EE);
    conv_w_all<<<896, 256, 0, stream>>>(wrel[0], wroot[0], wrel[1], wroot[1], wrel[2], wroot[2],
                                        B1t, B2t, B3t);

    // layer 1 (fo=256)
    mfma_gemm<0><<<dim3(MP / 128, 4), 256, 0, stream>>>(x, B1t, Yrel, hA, brel[0],
                                                        nullptr, nullptr, nullptr, nullptr, 517, 576, 256);
    agg_kernel<256><<<5000, 256, 0, stream>>>(Yrel, hA, off, psrc, pew);
    stats_kernel<256><<<64, 256, 0, stream>>>(hA, ss[0], sq[0]);

    // layer 2 (fo=128)
    mfma_gemm<1><<<dim3(MP / 128, 2), 256, 0, stream>>>(hA, B2t, Yrel, hB, brel[1],
                                                        ss[0], sq[0], bng[0], bnb[0], 256, 256, 128);
    agg_kernel<128><<<2500, 256, 0, stream>>>(Yrel, hB, off, psrc, pew);
    stats_kernel<128><<<64, 256, 0, stream>>>(hB, ss[1], sq[1]);

    // layer 3 (fo=64)
    mfma_gemm<1><<<dim3(MP / 128, 1), 256, 0, stream>>>(hB, B3t, Yrel, hC, brel[2],
                                                        ss[1], sq[1], bng[1], bnb[1], 128, 128, 64);
    agg_kernel<64><<<1250, 256, 0, stream>>>(Yrel, hC, off, psrc, pew);
    stats_kernel<64><<<64, 256, 0, stream>>>(hC, ss[2], sq[2]);

    head_kernel<<<2500, 256, 0, stream>>>(hC, ss[2], sq[2], bng[2], bnb[2], wlin, blin, tmp);
    lse_final<<<1, 1024, 0, stream>>>(tmp, out);
}

// Round 7
// 228.791 us; speedup vs baseline: 1.6068x; 1.0956x over previous
//
#include <hip/hip_runtime.h>
#include <math.h>

#define NN 10000
#define EE 160000
#define MP 10112   // 79*128, padded node count
#define EPSBN 1e-5f

typedef __attribute__((ext_vector_type(8))) short short8;
typedef __attribute__((ext_vector_type(4))) short short4v;
typedef __attribute__((ext_vector_type(4))) float f32x4;

__device__ __forceinline__ short f2bf(float f) {
    union { float f; unsigned u; } v; v.f = f;
    unsigned r = v.u + 0x7FFF + ((v.u >> 16) & 1);
    return (short)(r >> 16);
}
__device__ __forceinline__ float bf2f(unsigned short u) {
    union { unsigned u; float f; } v; v.u = ((unsigned)u) << 16;
    return v.f;
}
__device__ __forceinline__ void gload16(const short* g, short* l) {
    __builtin_amdgcn_global_load_lds((const __attribute__((address_space(1))) void*)g,
                                     (__attribute__((address_space(3))) void*)l, 16, 0, 0);
}

// ---------------- CSR build ----------------

__global__ void count_kernel(const int* __restrict__ dst, int* __restrict__ deg, int E) {
    int e = blockIdx.x * blockDim.x + threadIdx.x;
    if (e < E) atomicAdd(&deg[dst[e]], 1);
}

__global__ __launch_bounds__(1024) void scan_kernel(const int* __restrict__ deg, int* __restrict__ off,
                                                    int* __restrict__ cursor, int n) {
    __shared__ int sm[1024];
    const int C = 10;
    int t = threadIdx.x;
    int base = t * C;
    int loc[C];
    int acc = 0;
#pragma unroll
    for (int i = 0; i < C; i++) {
        int idx = base + i;
        int v = (idx < n) ? deg[idx] : 0;
        loc[i] = acc;
        acc += v;
    }
    sm[t] = acc;
    __syncthreads();
    for (int d = 1; d < 1024; d <<= 1) {
        int v = (t >= d) ? sm[t - d] : 0;
        __syncthreads();
        sm[t] += v;
        __syncthreads();
    }
    int prefix = (t > 0) ? sm[t - 1] : 0;
#pragma unroll
    for (int i = 0; i < C; i++) {
        int idx = base + i;
        if (idx < n) {
            int o = prefix + loc[i];
            off[idx] = o;
            cursor[idx] = o;
        }
    }
    if (t == 1023) off[n] = sm[1023];
}

__global__ void fill_kernel(const int* __restrict__ src, const int* __restrict__ dst,
                            const float* __restrict__ ew, int* __restrict__ cursor,
                            int* __restrict__ psrc, float* __restrict__ pew, int E) {
    int e = blockIdx.x * blockDim.x + threadIdx.x;
    if (e < E) {
        int d = dst[e];
        int slot = atomicAdd(&cursor[d], 1);
        psrc[slot] = src[e];
        pew[slot] = ew[e];
    }
}

// ---------------- x -> bf16 padded [MP,576] ----------------

__global__ void conv_x_kernel(const float* __restrict__ x, short* __restrict__ A) {
    int idx = blockIdx.x * 256 + threadIdx.x;   // one 8-col group per thread
    if (idx >= MP * 72) return;
    int row = idx / 72;
    int c0 = (idx % 72) * 8;
    short8 s;
    bool gr = (row < NN);
#pragma unroll
    for (int j = 0; j < 8; j++) {
        int c = c0 + j;
        float v = (gr && c < 517) ? x[(size_t)row * 517 + c] : 0.f;
        s[j] = f2bf(v);
    }
    *(short8*)&A[(size_t)row * 576 + c0] = s;
}

// ---------------- weights convert (all 3 layers in one kernel) ----------------

__global__ void conv_w_all(const float* __restrict__ w1r, const float* __restrict__ w1o,
                           const float* __restrict__ w2r, const float* __restrict__ w2o,
                           const float* __restrict__ w3r, const float* __restrict__ w3o,
                           short* __restrict__ B1, short* __restrict__ B2, short* __restrict__ B3) {
    int j = blockIdx.x;
    const float *Wr, *Wo;
    short* Bt;
    int K, Kp, fo, row;
    if (j < 512)      { row = j;       Wr = w1r; Wo = w1o; Bt = B1; K = 517; Kp = 576; fo = 256; }
    else if (j < 768) { row = j - 512; Wr = w2r; Wo = w2o; Bt = B2; K = 256; Kp = 256; fo = 128; }
    else              { row = j - 768; Wr = w3r; Wo = w3o; Bt = B3; K = 128; Kp = 128; fo = 64; }
    const float* W = (row < fo) ? Wr : Wo;
    int col = (row < fo) ? row : row - fo;
    for (int k = threadIdx.x; k < Kp; k += 256) {
        short v = 0;
        if (k < K) v = f2bf(W[(size_t)k * fo + col]);
        Bt[(size_t)row * Kp + k] = v;
    }
}

// ---------------- MFMA GEMM, double-buffered pipeline ----------------
// MODE 0: A = Abf bf16 [MP,Kp] pre-padded, staged via global_load_lds
// MODE 1: A = Af32 f32 [MP,K], BN(scale/shift from sums)+ReLU fused, reg-staged
// Each wave: rows [wid*16, wid*16+16), all BN cols. Writes Yrel bf16 + Hroot f32(+brel).

template <int MODE, int BM, int BN, int NT>
__global__ __launch_bounds__(NT) void mfma_gemm(const short* __restrict__ Abf,
                                                const float* __restrict__ Af32,
                                                const short* __restrict__ Bt,
                                                short* __restrict__ Yrel,
                                                float* __restrict__ Hroot,
                                                const float* __restrict__ brel,
                                                const float* __restrict__ ssum,
                                                const float* __restrict__ ssumsq,
                                                const float* __restrict__ bng,
                                                const float* __restrict__ bnb,
                                                int K, int Kp, int fo) {
    const int N_REP = BN / 16;
    const int ACH = BM * 8 / NT;    // A 16B chunks per thread (MODE 0)
    const int BCH = BN * 8 / NT;    // B 16B chunks per thread
    const int AF4 = BM * 16 / NT;   // A float4 per thread (MODE 1)

    __shared__ short Als[2][BM * 64];
    __shared__ short Bls[2][BN * 64];
    __shared__ float scs[256], shs[256];

    int m0 = blockIdx.x * BM;
    int n0 = blockIdx.y * BN;
    int t = threadIdx.x;
    int lane = t & 63;
    int wid = t >> 6;

    if (MODE == 1) {
        for (int f = t; f < K; f += NT) {
            float mean = ssum[f] / (float)NN;
            float var = ssumsq[f] / (float)NN - mean * mean;
            var = fmaxf(var, 0.f);
            float sc = bng[f] * rsqrtf(var + EPSBN);
            scs[f] = sc;
            shs[f] = bnb[f] - mean * sc;
        }
        __syncthreads();
    }

    f32x4 acc[N_REP];
#pragma unroll
    for (int j = 0; j < N_REP; j++) acc[j] = (f32x4){0.f, 0.f, 0.f, 0.f};

    f32x4 ld[AF4 > 0 ? AF4 : 1];

    auto stageB = [&](int buf, int k0) {
#pragma unroll
        for (int i = 0; i < BCH; i++) {
            int idx = i * NT + t;
            int row = idx >> 3;
            int pc = idx & 7;
            gload16(Bt + (size_t)(n0 + row) * Kp + k0 + ((pc ^ (row & 7)) << 3), &Bls[buf][idx << 3]);
        }
    };
    auto stageA0 = [&](int buf, int k0) {
#pragma unroll
        for (int i = 0; i < ACH; i++) {
            int idx = i * NT + t;
            int row = idx >> 3;
            int pc = idx & 7;
            gload16(Abf + (size_t)(m0 + row) * Kp + k0 + ((pc ^ (row & 7)) << 3), &Als[buf][idx << 3]);
        }
    };
    auto loadA1 = [&](int k0) {
#pragma unroll
        for (int i = 0; i < AF4; i++) {
            int idx = i * NT + t;
            int row = idx >> 4;
            int fc = idx & 15;
            ld[i] = *(const f32x4*)(Af32 + (size_t)(m0 + row) * K + k0 + (fc << 2));
        }
    };
    auto writeA1 = [&](int buf, int k0) {
#pragma unroll
        for (int i = 0; i < AF4; i++) {
            int idx = i * NT + t;
            int row = idx >> 4;
            int fc = idx & 15;
            int kb = k0 + (fc << 2);
            short4v s;
#pragma unroll
            for (int j = 0; j < 4; j++) s[j] = f2bf(fmaxf(0.f, ld[i][j] * scs[kb + j] + shs[kb + j]));
            *(short4v*)&Als[buf][row * 64 + (((fc >> 1) ^ (row & 7)) << 3) + ((fc & 1) << 2)] = s;
        }
    };
    auto compute = [&](int buf) {
#pragma unroll
        for (int kk = 0; kk < 2; kk++) {
            int cc = kk * 4 + (lane >> 4);
            short8 af;
            {
                int row = wid * 16 + (lane & 15);
                af = *(const short8*)&Als[buf][(row * 8 + (cc ^ (row & 7))) * 8];
            }
#pragma unroll
            for (int ni = 0; ni < N_REP; ni++) {
                int row = ni * 16 + (lane & 15);
                short8 b8 = *(const short8*)&Bls[buf][(row * 8 + (cc ^ (row & 7))) * 8];
                acc[ni] = __builtin_amdgcn_mfma_f32_16x16x32_bf16(af, b8, acc[ni], 0, 0, 0);
            }
        }
    };

    int nsteps = Kp / 64;
    // prologue: stage step 0 into buf 0
    if (MODE == 0) stageA0(0, 0);
    else { loadA1(0); writeA1(0, 0); }
    stageB(0, 0);
    __syncthreads();

    int cur = 0;
    for (int s = 0; s < nsteps; s++) {
        int k1 = (s + 1) * 64;
        bool nxt = (s + 1 < nsteps);
        if (nxt) {
            if (MODE == 0) stageA0(cur ^ 1, k1);
            else loadA1(k1);
            stageB(cur ^ 1, k1);
        }
        compute(cur);
        if (nxt && MODE == 1) writeA1(cur ^ 1, k1);
        __syncthreads();
        cur ^= 1;
    }

    // epilogue
#pragma unroll
    for (int ni = 0; ni < N_REP; ni++) {
        int gn = n0 + ni * 16 + (lane & 15);
        int row0 = m0 + wid * 16 + (lane >> 4) * 4;
        f32x4 v = acc[ni];
        if (gn < fo) {
#pragma unroll
            for (int r = 0; r < 4; r++) Yrel[(size_t)(row0 + r) * fo + gn] = f2bf(v[r]);
        } else {
            float bb = brel[gn - fo];
#pragma unroll
            for (int r = 0; r < 4; r++) Hroot[(size_t)(row0 + r) * fo + (gn - fo)] = v[r] + bb;
        }
    }
}

// ---------------- pure aggregation: hio[n,f] += sum_e w*Yrel[src,f] ----------------

template <int FO>
__global__ __launch_bounds__(256) void agg_kernel(const short* __restrict__ Yrel,
                                                  float* __restrict__ hio,
                                                  const int* __restrict__ off,
                                                  const int* __restrict__ psrc,
                                                  const float* __restrict__ pew) {
    const int G = FO / 2;
    const int NPB = 256 / G;
    int t = threadIdx.x;
    int g = t / G;
    int tf = t % G;
    int f = tf * 2;
    int n = blockIdx.x * NPB + g;
    if (n >= NN) return;

    float a0 = 0.f, a1 = 0.f;
    int e0 = off[n], e1 = off[n + 1];
    int e = e0;
    for (; e + 1 < e1; e += 2) {
        int s0i = psrc[e], s1i = psrc[e + 1];
        float w0 = pew[e], w1 = pew[e + 1];
        unsigned p0 = *(const unsigned*)(Yrel + (size_t)s0i * FO + f);
        unsigned p1 = *(const unsigned*)(Yrel + (size_t)s1i * FO + f);
        a0 += w0 * bf2f((unsigned short)(p0 & 0xffff));
        a1 += w0 * bf2f((unsigned short)(p0 >> 16));
        a0 += w1 * bf2f((unsigned short)(p1 & 0xffff));
        a1 += w1 * bf2f((unsigned short)(p1 >> 16));
    }
    if (e < e1) {
        int s0i = psrc[e];
        float w0 = pew[e];
        unsigned p0 = *(const unsigned*)(Yrel + (size_t)s0i * FO + f);
        a0 += w0 * bf2f((unsigned short)(p0 & 0xffff));
        a1 += w0 * bf2f((unsigned short)(p0 >> 16));
    }
    size_t o = (size_t)n * FO + f;
    hio[o]     += a0;
    hio[o + 1] += a1;
}

// ---------------- BN stats pass ----------------

template <int FO>
__global__ __launch_bounds__(256) void stats_kernel(const float* __restrict__ hio,
                                                    float* __restrict__ ssum,
                                                    float* __restrict__ ssumsq) {
    const int LANES = 256 / FO;
    const int RPB = (NN + 63) / 64;
    __shared__ float sms[256], smq[256];
    int t = threadIdx.x;
    int f = t % FO;
    int rl = t / FO;
    int r0 = blockIdx.x * RPB;
    int r1 = r0 + RPB;
    if (r1 > NN) r1 = NN;
    float s = 0.f, q = 0.f;
    for (int r = r0 + rl; r < r1; r += LANES) {
        float v = hio[(size_t)r * FO + f];
        s += v;
        q += v * v;
    }
    if (LANES > 1) {
        sms[t] = s;
        smq[t] = q;
        __syncthreads();
        if (rl == 0) {
#pragma unroll
            for (int l = 1; l < LANES; l++) {
                s += sms[l * FO + f];
                q += smq[l * FO + f];
            }
        }
    }
    if (rl == 0) {
        atomicAdd(&ssum[f], s);
        atomicAdd(&ssumsq[f], q);
    }
}

// ---------------- head: BN3 + ReLU + dot(wlin) + log_sigmoid ----------------

__global__ void head_kernel(const float* __restrict__ hio,
                            const float* __restrict__ ssum, const float* __restrict__ ssumsq,
                            const float* __restrict__ g3, const float* __restrict__ b3,
                            const float* __restrict__ wlin, const float* __restrict__ blin,
                            float* __restrict__ tmp) {
    int lane = threadIdx.x & 63;
    int wv = threadIdx.x >> 6;
    int n = blockIdx.x * 4 + wv;
    float mean = ssum[lane] / (float)NN;
    float var = ssumsq[lane] / (float)NN - mean * mean;
    var = fmaxf(var, 0.f);
    float sc = g3[lane] * rsqrtf(var + EPSBN);
    float sh = b3[lane] - mean * sc;
    float v = fmaxf(0.f, hio[(size_t)n * 64 + lane] * sc + sh);
    float p = v * wlin[lane];
#pragma unroll
    for (int o = 32; o > 0; o >>= 1) p += __shfl_down(p, o, 64);
    if (lane == 0) {
        float x = p + blin[0];
        float ls = (x >= 0.f) ? (-log1pf(expf(-x))) : (x - log1pf(expf(x)));
        tmp[n] = ls;
    }
}

// ---------------- logsumexp + final subtract (one block) ----------------

__global__ __launch_bounds__(1024) void lse_final(const float* __restrict__ tmp, float* __restrict__ out) {
    __shared__ float sm[1024];
    int t = threadIdx.x;
    float m = -INFINITY;
    for (int i = t; i < NN; i += 1024) m = fmaxf(m, tmp[i]);
    sm[t] = m;
    __syncthreads();
    for (int s = 512; s > 0; s >>= 1) {
        if (t < s) sm[t] = fmaxf(sm[t], sm[t + s]);
        __syncthreads();
    }
    float M = sm[0];
    __syncthreads();
    float acc = 0.f;
    for (int i = t; i < NN; i += 1024) acc += expf(tmp[i] - M);
    sm[t] = acc;
    __syncthreads();
    for (int s = 512; s > 0; s >>= 1) {
        if (t < s) sm[t] += sm[t + s];
        __syncthreads();
    }
    float L = M + logf(sm[0]);
    for (int i = t; i < NN; i += 1024) out[i] = tmp[i] - L;
}

// ---------------- launch ----------------

extern "C" void kernel_launch(void* const* d_in, const int* in_sizes, int n_in,
                              void* d_out, int out_size, void* d_ws, size_t ws_size,
                              hipStream_t stream) {
    const float* x  = (const float*)d_in[0];
    const int* ei   = (const int*)d_in[1];
    const float* ew = (const float*)d_in[2];
    const int* src = ei;
    const int* dst = ei + EE;

    const float* wrel[3]  = { (const float*)d_in[3],  (const float*)d_in[8],  (const float*)d_in[13] };
    const float* brel[3]  = { (const float*)d_in[4],  (const float*)d_in[9],  (const float*)d_in[14] };
    const float* wroot[3] = { (const float*)d_in[5],  (const float*)d_in[10], (const float*)d_in[15] };
    const float* bng[3]   = { (const float*)d_in[6],  (const float*)d_in[11], (const float*)d_in[16] };
    const float* bnb[3]   = { (const float*)d_in[7],  (const float*)d_in[12], (const float*)d_in[17] };
    const float* wlin = (const float*)d_in[18];
    const float* blin = (const float*)d_in[19];
    float* out = (float*)d_out;

    char* p = (char*)d_ws;
    auto alloc = [&](size_t bytes) { char* r = p; p += (bytes + 255) & ~(size_t)255; return r; };

    int*   deg     = (int*)alloc(NN * 4);           // memset region start
    float* ssumAll = (float*)alloc(1536 * 4);       // 3 layers x (sum[256]+sumsq[256])
    int*   off     = (int*)alloc((NN + 4) * 4);
    int*   cursor  = (int*)alloc(NN * 4);
    int*   psrc    = (int*)alloc(EE * 4);
    float* pew     = (float*)alloc(EE * 4);
    short* A1      = (short*)alloc((size_t)MP * 576 * 2);
    short* B1t     = (short*)alloc((size_t)512 * 576 * 2);
    short* B2t     = (short*)alloc((size_t)256 * 256 * 2);
    short* B3t     = (short*)alloc((size_t)128 * 128 * 2);
    short* Yrel    = (short*)alloc((size_t)MP * 256 * 2);
    float* hA      = (float*)alloc((size_t)MP * 256 * 4);
    float* hB      = (float*)alloc((size_t)MP * 128 * 4);
    float* hC      = (float*)alloc((size_t)MP * 64 * 4);
    float* tmp     = (float*)alloc(NN * 4);

    float* ss[3]  = { ssumAll,       ssumAll + 512,  ssumAll + 1024 };
    float* sq[3]  = { ssumAll + 256, ssumAll + 768,  ssumAll + 1280 };

    hipMemsetAsync(deg, 0, (size_t)((char*)(ssumAll + 1536) - (char*)deg), stream);

    count_kernel<<<(EE + 255) / 256, 256, 0, stream>>>(dst, deg, EE);
    scan_kernel<<<1, 1024, 0, stream>>>(deg, off, cursor, NN);
    fill_kernel<<<(EE + 255) / 256, 256, 0, stream>>>(src, dst, ew, cursor, psrc, pew, EE);
    conv_x_kernel<<<(MP * 72 + 255) / 256, 256, 0, stream>>>(x, A1);
    conv_w_all<<<896, 256, 0, stream>>>(wrel[0], wroot[0], wrel[1], wroot[1], wrel[2], wroot[2],
                                        B1t, B2t, B3t);

    // layer 1 (K=576->BM=128,BN=128, 512 thr): grid 79x4
    mfma_gemm<0, 128, 128, 512><<<dim3(MP / 128, 4), 512, 0, stream>>>(
        A1, nullptr, B1t, Yrel, hA, brel[0], nullptr, nullptr, nullptr, nullptr, 576, 576, 256);
    agg_kernel<256><<<5000, 256, 0, stream>>>(Yrel, hA, off, psrc, pew);
    stats_kernel<256><<<64, 256, 0, stream>>>(hA, ss[0], sq[0]);

    // layer 2 (K=256, BM=64,BN=128): grid 158x2
    mfma_gemm<1, 64, 128, 256><<<dim3(MP / 64, 2), 256, 0, stream>>>(
        nullptr, hA, B2t, Yrel, hB, brel[1], ss[0], sq[0], bng[0], bnb[0], 256, 256, 128);
    agg_kernel<128><<<2500, 256, 0, stream>>>(Yrel, hB, off, psrc, pew);
    stats_kernel<128><<<64, 256, 0, stream>>>(hB, ss[1], sq[1]);

    // layer 3 (K=128, BM=64,BN=64): grid 158x2
    mfma_gemm<1, 64, 64, 256><<<dim3(MP / 64, 2), 256, 0, stream>>>(
        nullptr, hB, B3t, Yrel, hC, brel[2], ss[1], sq[1], bng[1], bnb[1], 128, 128, 64);
    agg_kernel<64><<<1250, 256, 0, stream>>>(Yrel, hC, off, psrc, pew);
    stats_kernel<64><<<64, 256, 0, stream>>>(hC, ss[2], sq[2]);

    head_kernel<<<2500, 256, 0, stream>>>(hC, ss[2], sq[2], bng[2], bnb[2], wlin, blin, tmp);
    lse_final<<<1, 1024, 0, stream>>>(tmp, out);
}

// Round 8
// 176.451 us; speedup vs baseline: 2.0834x; 1.2966x over previous
//
#include <hip/hip_runtime.h>
#include <math.h>

#define NN 10000
#define EE 160000
#define MP 10112   // 79*128, padded node count
#define EPSBN 1e-5f

typedef __attribute__((ext_vector_type(8))) short short8;
typedef __attribute__((ext_vector_type(4))) short short4v;
typedef __attribute__((ext_vector_type(4))) float f32x4;

__device__ __forceinline__ short f2bf(float f) {
    union { float f; unsigned u; } v; v.f = f;
    unsigned r = v.u + 0x7FFF + ((v.u >> 16) & 1);
    return (short)(r >> 16);
}
__device__ __forceinline__ float bf2f(unsigned short u) {
    union { unsigned u; float f; } v; v.u = ((unsigned)u) << 16;
    return v.f;
}
__device__ __forceinline__ void gload16(const short* g, short* l) {
    __builtin_amdgcn_global_load_lds((const __attribute__((address_space(1))) void*)g,
                                     (__attribute__((address_space(3))) void*)l, 16, 0, 0);
}

// ---------------- CSR build ----------------

__global__ void count_kernel(const int* __restrict__ dst, int* __restrict__ deg, int E) {
    int e = blockIdx.x * blockDim.x + threadIdx.x;
    if (e < E) atomicAdd(&deg[dst[e]], 1);
}

__global__ __launch_bounds__(1024) void scan_kernel(const int* __restrict__ deg, int* __restrict__ off,
                                                    int* __restrict__ cursor, int n) {
    __shared__ int sm[1024];
    const int C = 10;
    int t = threadIdx.x;
    int base = t * C;
    int loc[C];
    int acc = 0;
#pragma unroll
    for (int i = 0; i < C; i++) {
        int idx = base + i;
        int v = (idx < n) ? deg[idx] : 0;
        loc[i] = acc;
        acc += v;
    }
    sm[t] = acc;
    __syncthreads();
    for (int d = 1; d < 1024; d <<= 1) {
        int v = (t >= d) ? sm[t - d] : 0;
        __syncthreads();
        sm[t] += v;
        __syncthreads();
    }
    int prefix = (t > 0) ? sm[t - 1] : 0;
#pragma unroll
    for (int i = 0; i < C; i++) {
        int idx = base + i;
        if (idx < n) {
            int o = prefix + loc[i];
            off[idx] = o;
            cursor[idx] = o;
        }
    }
    if (t == 1023) off[n] = sm[1023];
}

__global__ void fill_kernel(const int* __restrict__ src, const int* __restrict__ dst,
                            const float* __restrict__ ew, int* __restrict__ cursor,
                            int* __restrict__ psrc, float* __restrict__ pew, int E) {
    int e = blockIdx.x * blockDim.x + threadIdx.x;
    if (e < E) {
        int d = dst[e];
        int slot = atomicAdd(&cursor[d], 1);
        psrc[slot] = src[e];
        pew[slot] = ew[e];
    }
}

// ---------------- x -> bf16 padded [MP,576] ----------------

__global__ void conv_x_kernel(const float* __restrict__ x, short* __restrict__ A) {
    int idx = blockIdx.x * 256 + threadIdx.x;   // one 8-col group per thread
    if (idx >= MP * 72) return;
    int row = idx / 72;
    int c0 = (idx % 72) * 8;
    short8 s;
    bool gr = (row < NN);
#pragma unroll
    for (int j = 0; j < 8; j++) {
        int c = c0 + j;
        float v = (gr && c < 517) ? x[(size_t)row * 517 + c] : 0.f;
        s[j] = f2bf(v);
    }
    *(short8*)&A[(size_t)row * 576 + c0] = s;
}

// ---------------- weights convert (all 3 layers in one kernel) ----------------

__global__ void conv_w_all(const float* __restrict__ w1r, const float* __restrict__ w1o,
                           const float* __restrict__ w2r, const float* __restrict__ w2o,
                           const float* __restrict__ w3r, const float* __restrict__ w3o,
                           short* __restrict__ B1, short* __restrict__ B2, short* __restrict__ B3) {
    int j = blockIdx.x;
    const float *Wr, *Wo;
    short* Bt;
    int K, Kp, fo, row;
    if (j < 512)      { row = j;       Wr = w1r; Wo = w1o; Bt = B1; K = 517; Kp = 576; fo = 256; }
    else if (j < 768) { row = j - 512; Wr = w2r; Wo = w2o; Bt = B2; K = 256; Kp = 256; fo = 128; }
    else              { row = j - 768; Wr = w3r; Wo = w3o; Bt = B3; K = 128; Kp = 128; fo = 64; }
    const float* W = (row < fo) ? Wr : Wo;
    int col = (row < fo) ? row : row - fo;
    for (int k = threadIdx.x; k < Kp; k += 256) {
        short v = 0;
        if (k < K) v = f2bf(W[(size_t)k * fo + col]);
        Bt[(size_t)row * Kp + k] = v;
    }
}

// ---------------- MFMA GEMM, double-buffered pipeline ----------------
// MODE 0: A = Abf bf16 [MP,Kp] pre-padded, staged via global_load_lds
// MODE 1: A = Af32 f32 [MP,K], BN(scale/shift from sums)+ReLU fused, reg-staged

template <int MODE, int BM, int BN, int NT>
__global__ __launch_bounds__(NT) void mfma_gemm(const short* __restrict__ Abf,
                                                const float* __restrict__ Af32,
                                                const short* __restrict__ Bt,
                                                short* __restrict__ Yrel,
                                                float* __restrict__ Hroot,
                                                const float* __restrict__ brel,
                                                const float* __restrict__ ssum,
                                                const float* __restrict__ ssumsq,
                                                const float* __restrict__ bng,
                                                const float* __restrict__ bnb,
                                                int K, int Kp, int fo) {
    const int N_REP = BN / 16;
    const int ACH = BM * 8 / NT;
    const int BCH = BN * 8 / NT;
    const int AF4 = BM * 16 / NT;

    __shared__ short Als[2][BM * 64];
    __shared__ short Bls[2][BN * 64];
    __shared__ float scs[256], shs[256];

    int m0 = blockIdx.x * BM;
    int n0 = blockIdx.y * BN;
    int t = threadIdx.x;
    int lane = t & 63;
    int wid = t >> 6;

    if (MODE == 1) {
        for (int f = t; f < K; f += NT) {
            float mean = ssum[f] / (float)NN;
            float var = ssumsq[f] / (float)NN - mean * mean;
            var = fmaxf(var, 0.f);
            float sc = bng[f] * rsqrtf(var + EPSBN);
            scs[f] = sc;
            shs[f] = bnb[f] - mean * sc;
        }
        __syncthreads();
    }

    f32x4 acc[N_REP];
#pragma unroll
    for (int j = 0; j < N_REP; j++) acc[j] = (f32x4){0.f, 0.f, 0.f, 0.f};

    f32x4 ld[AF4 > 0 ? AF4 : 1];

    auto stageB = [&](int buf, int k0) {
#pragma unroll
        for (int i = 0; i < BCH; i++) {
            int idx = i * NT + t;
            int row = idx >> 3;
            int pc = idx & 7;
            gload16(Bt + (size_t)(n0 + row) * Kp + k0 + ((pc ^ (row & 7)) << 3), &Bls[buf][idx << 3]);
        }
    };
    auto stageA0 = [&](int buf, int k0) {
#pragma unroll
        for (int i = 0; i < ACH; i++) {
            int idx = i * NT + t;
            int row = idx >> 3;
            int pc = idx & 7;
            gload16(Abf + (size_t)(m0 + row) * Kp + k0 + ((pc ^ (row & 7)) << 3), &Als[buf][idx << 3]);
        }
    };
    auto loadA1 = [&](int k0) {
#pragma unroll
        for (int i = 0; i < AF4; i++) {
            int idx = i * NT + t;
            int row = idx >> 4;
            int fc = idx & 15;
            ld[i] = *(const f32x4*)(Af32 + (size_t)(m0 + row) * K + k0 + (fc << 2));
        }
    };
    auto writeA1 = [&](int buf, int k0) {
#pragma unroll
        for (int i = 0; i < AF4; i++) {
            int idx = i * NT + t;
            int row = idx >> 4;
            int fc = idx & 15;
            int kb = k0 + (fc << 2);
            short4v s;
#pragma unroll
            for (int j = 0; j < 4; j++) s[j] = f2bf(fmaxf(0.f, ld[i][j] * scs[kb + j] + shs[kb + j]));
            *(short4v*)&Als[buf][row * 64 + (((fc >> 1) ^ (row & 7)) << 3) + ((fc & 1) << 2)] = s;
        }
    };
    auto compute = [&](int buf) {
#pragma unroll
        for (int kk = 0; kk < 2; kk++) {
            int cc = kk * 4 + (lane >> 4);
            short8 af;
            {
                int row = wid * 16 + (lane & 15);
                af = *(const short8*)&Als[buf][(row * 8 + (cc ^ (row & 7))) * 8];
            }
#pragma unroll
            for (int ni = 0; ni < N_REP; ni++) {
                int row = ni * 16 + (lane & 15);
                short8 b8 = *(const short8*)&Bls[buf][(row * 8 + (cc ^ (row & 7))) * 8];
                acc[ni] = __builtin_amdgcn_mfma_f32_16x16x32_bf16(af, b8, acc[ni], 0, 0, 0);
            }
        }
    };

    int nsteps = Kp / 64;
    if (MODE == 0) stageA0(0, 0);
    else { loadA1(0); writeA1(0, 0); }
    stageB(0, 0);
    __syncthreads();

    int cur = 0;
    for (int s = 0; s < nsteps; s++) {
        int k1 = (s + 1) * 64;
        bool nxt = (s + 1 < nsteps);
        if (nxt) {
            if (MODE == 0) stageA0(cur ^ 1, k1);
            else loadA1(k1);
            stageB(cur ^ 1, k1);
        }
        compute(cur);
        if (nxt && MODE == 1) writeA1(cur ^ 1, k1);
        __syncthreads();
        cur ^= 1;
    }

#pragma unroll
    for (int ni = 0; ni < N_REP; ni++) {
        int gn = n0 + ni * 16 + (lane & 15);
        int row0 = m0 + wid * 16 + (lane >> 4) * 4;
        f32x4 v = acc[ni];
        if (gn < fo) {
#pragma unroll
            for (int r = 0; r < 4; r++) Yrel[(size_t)(row0 + r) * fo + gn] = f2bf(v[r]);
        } else {
            float bb = brel[gn - fo];
#pragma unroll
            for (int r = 0; r < 4; r++) Hroot[(size_t)(row0 + r) * fo + (gn - fo)] = v[r] + bb;
        }
    }
}

// ---------------- pure aggregation: hio[n,f] += sum_e w*Yrel[src,f] ----------------

template <int FO>
__global__ __launch_bounds__(256) void agg_kernel(const short* __restrict__ Yrel,
                                                  float* __restrict__ hio,
                                                  const int* __restrict__ off,
                                                  const int* __restrict__ psrc,
                                                  const float* __restrict__ pew) {
    const int G = FO / 2;
    const int NPB = 256 / G;
    int t = threadIdx.x;
    int g = t / G;
    int tf = t % G;
    int f = tf * 2;
    int n = blockIdx.x * NPB + g;
    if (n >= NN) return;

    float a0 = 0.f, a1 = 0.f;
    int e0 = off[n], e1 = off[n + 1];
    int e = e0;
    for (; e + 1 < e1; e += 2) {
        int s0i = psrc[e], s1i = psrc[e + 1];
        float w0 = pew[e], w1 = pew[e + 1];
        unsigned p0 = *(const unsigned*)(Yrel + (size_t)s0i * FO + f);
        unsigned p1 = *(const unsigned*)(Yrel + (size_t)s1i * FO + f);
        a0 += w0 * bf2f((unsigned short)(p0 & 0xffff));
        a1 += w0 * bf2f((unsigned short)(p0 >> 16));
        a0 += w1 * bf2f((unsigned short)(p1 & 0xffff));
        a1 += w1 * bf2f((unsigned short)(p1 >> 16));
    }
    if (e < e1) {
        int s0i = psrc[e];
        float w0 = pew[e];
        unsigned p0 = *(const unsigned*)(Yrel + (size_t)s0i * FO + f);
        a0 += w0 * bf2f((unsigned short)(p0 & 0xffff));
        a1 += w0 * bf2f((unsigned short)(p0 >> 16));
    }
    size_t o = (size_t)n * FO + f;
    hio[o]     += a0;
    hio[o + 1] += a1;
}

// ---------------- BN stats: 2-stage deterministic reduction ----------------
// stage 1: 256 blocks, f32x4 per thread, per-block partials (no atomics)

template <int FO>
__global__ __launch_bounds__(256) void stats_part(const float* __restrict__ hio,
                                                  float* __restrict__ pS,
                                                  float* __restrict__ pQ) {
    const int FG = FO / 4;          // feature groups of 4
    const int ROWL = 256 / FG;      // row lanes
    const int RPB = (NN + 255) / 256;  // 40 rows per block
    __shared__ f32x4 sms[256], smq[256];
    int t = threadIdx.x;
    int fg = t % FG;
    int rl = t / FG;
    int r0 = blockIdx.x * RPB;
    int r1 = r0 + RPB;
    if (r1 > NN) r1 = NN;
    f32x4 s = (f32x4){0.f, 0.f, 0.f, 0.f};
    f32x4 q = (f32x4){0.f, 0.f, 0.f, 0.f};
    for (int r = r0 + rl; r < r1; r += ROWL) {
        f32x4 v = *(const f32x4*)(hio + (size_t)r * FO + fg * 4);
        s += v;
        q += v * v;
    }
    sms[t] = s;
    smq[t] = q;
    __syncthreads();
    if (rl == 0) {
#pragma unroll
        for (int l = 1; l < ROWL; l++) {
            s += sms[l * FG + fg];
            q += smq[l * FG + fg];
        }
        *(f32x4*)(pS + (size_t)blockIdx.x * FO + fg * 4) = s;
        *(f32x4*)(pQ + (size_t)blockIdx.x * FO + fg * 4) = q;
    }
}

// stage 2: one block per feature, 256 threads read 256 partials, tree reduce, plain store
__global__ __launch_bounds__(256) void stats_reduce(const float* __restrict__ pS,
                                                    const float* __restrict__ pQ,
                                                    float* __restrict__ ssum,
                                                    float* __restrict__ ssumsq,
                                                    int FO) {
    int f = blockIdx.x;
    int t = threadIdx.x;
    float s = pS[(size_t)t * FO + f];
    float q = pQ[(size_t)t * FO + f];
#pragma unroll
    for (int o = 32; o > 0; o >>= 1) {
        s += __shfl_down(s, o, 64);
        q += __shfl_down(q, o, 64);
    }
    __shared__ float smS[4], smQ[4];
    int lane = t & 63, w = t >> 6;
    if (lane == 0) { smS[w] = s; smQ[w] = q; }
    __syncthreads();
    if (t == 0) {
        ssum[f]   = smS[0] + smS[1] + smS[2] + smS[3];
        ssumsq[f] = smQ[0] + smQ[1] + smQ[2] + smQ[3];
    }
}

// ---------------- head: BN3 + ReLU + dot(wlin) + log_sigmoid ----------------

__global__ void head_kernel(const float* __restrict__ hio,
                            const float* __restrict__ ssum, const float* __restrict__ ssumsq,
                            const float* __restrict__ g3, const float* __restrict__ b3,
                            const float* __restrict__ wlin, const float* __restrict__ blin,
                            float* __restrict__ tmp) {
    int lane = threadIdx.x & 63;
    int wv = threadIdx.x >> 6;
    int n = blockIdx.x * 4 + wv;
    float mean = ssum[lane] / (float)NN;
    float var = ssumsq[lane] / (float)NN - mean * mean;
    var = fmaxf(var, 0.f);
    float sc = g3[lane] * rsqrtf(var + EPSBN);
    float sh = b3[lane] - mean * sc;
    float v = fmaxf(0.f, hio[(size_t)n * 64 + lane] * sc + sh);
    float p = v * wlin[lane];
#pragma unroll
    for (int o = 32; o > 0; o >>= 1) p += __shfl_down(p, o, 64);
    if (lane == 0) {
        float x = p + blin[0];
        float ls = (x >= 0.f) ? (-log1pf(expf(-x))) : (x - log1pf(expf(x)));
        tmp[n] = ls;
    }
}

// ---------------- logsumexp + final subtract (one block) ----------------

__global__ __launch_bounds__(1024) void lse_final(const float* __restrict__ tmp, float* __restrict__ out) {
    __shared__ float sm[1024];
    int t = threadIdx.x;
    float m = -INFINITY;
    for (int i = t; i < NN; i += 1024) m = fmaxf(m, tmp[i]);
    sm[t] = m;
    __syncthreads();
    for (int s = 512; s > 0; s >>= 1) {
        if (t < s) sm[t] = fmaxf(sm[t], sm[t + s]);
        __syncthreads();
    }
    float M = sm[0];
    __syncthreads();
    float acc = 0.f;
    for (int i = t; i < NN; i += 1024) acc += expf(tmp[i] - M);
    sm[t] = acc;
    __syncthreads();
    for (int s = 512; s > 0; s >>= 1) {
        if (t < s) sm[t] += sm[t + s];
        __syncthreads();
    }
    float L = M + logf(sm[0]);
    for (int i = t; i < NN; i += 1024) out[i] = tmp[i] - L;
}

// ---------------- launch ----------------

extern "C" void kernel_launch(void* const* d_in, const int* in_sizes, int n_in,
                              void* d_out, int out_size, void* d_ws, size_t ws_size,
                              hipStream_t stream) {
    const float* x  = (const float*)d_in[0];
    const int* ei   = (const int*)d_in[1];
    const float* ew = (const float*)d_in[2];
    const int* src = ei;
    const int* dst = ei + EE;

    const float* wrel[3]  = { (const float*)d_in[3],  (const float*)d_in[8],  (const float*)d_in[13] };
    const float* brel[3]  = { (const float*)d_in[4],  (const float*)d_in[9],  (const float*)d_in[14] };
    const float* wroot[3] = { (const float*)d_in[5],  (const float*)d_in[10], (const float*)d_in[15] };
    const float* bng[3]   = { (const float*)d_in[6],  (const float*)d_in[11], (const float*)d_in[16] };
    const float* bnb[3]   = { (const float*)d_in[7],  (const float*)d_in[12], (const float*)d_in[17] };
    const float* wlin = (const float*)d_in[18];
    const float* blin = (const float*)d_in[19];
    float* out = (float*)d_out;

    char* p = (char*)d_ws;
    auto alloc = [&](size_t bytes) { char* r = p; p += (bytes + 255) & ~(size_t)255; return r; };

    int*   deg     = (int*)alloc(NN * 4);           // memset region start
    float* ssumAll = (float*)alloc(1536 * 4);
    int*   off     = (int*)alloc((NN + 4) * 4);
    int*   cursor  = (int*)alloc(NN * 4);
    int*   psrc    = (int*)alloc(EE * 4);
    float* pew     = (float*)alloc(EE * 4);
    short* A1      = (short*)alloc((size_t)MP * 576 * 2);
    short* B1t     = (short*)alloc((size_t)512 * 576 * 2);
    short* B2t     = (short*)alloc((size_t)256 * 256 * 2);
    short* B3t     = (short*)alloc((size_t)128 * 128 * 2);
    short* Yrel    = (short*)alloc((size_t)MP * 256 * 2);
    float* hA      = (float*)alloc((size_t)MP * 256 * 4);
    float* hB      = (float*)alloc((size_t)MP * 128 * 4);
    float* hC      = (float*)alloc((size_t)MP * 64 * 4);
    float* tmp     = (float*)alloc(NN * 4);
    float* pS      = (float*)alloc((size_t)256 * 256 * 4);
    float* pQ      = (float*)alloc((size_t)256 * 256 * 4);

    float* ss[3]  = { ssumAll,       ssumAll + 512,  ssumAll + 1024 };
    float* sq[3]  = { ssumAll + 256, ssumAll + 768,  ssumAll + 1280 };

    hipMemsetAsync(deg, 0, (size_t)((char*)(ssumAll + 1536) - (char*)deg), stream);

    count_kernel<<<(EE + 255) / 256, 256, 0, stream>>>(dst, deg, EE);
    scan_kernel<<<1, 1024, 0, stream>>>(deg, off, cursor, NN);
    fill_kernel<<<(EE + 255) / 256, 256, 0, stream>>>(src, dst, ew, cursor, psrc, pew, EE);
    conv_x_kernel<<<(MP * 72 + 255) / 256, 256, 0, stream>>>(x, A1);
    conv_w_all<<<896, 256, 0, stream>>>(wrel[0], wroot[0], wrel[1], wroot[1], wrel[2], wroot[2],
                                        B1t, B2t, B3t);

    // layer 1 (K=576, BM=128,BN=128, 512 thr): grid 79x4
    mfma_gemm<0, 128, 128, 512><<<dim3(MP / 128, 4), 512, 0, stream>>>(
        A1, nullptr, B1t, Yrel, hA, brel[0], nullptr, nullptr, nullptr, nullptr, 576, 576, 256);
    agg_kernel<256><<<5000, 256, 0, stream>>>(Yrel, hA, off, psrc, pew);
    stats_part<256><<<256, 256, 0, stream>>>(hA, pS, pQ);
    stats_reduce<<<256, 256, 0, stream>>>(pS, pQ, ss[0], sq[0], 256);

    // layer 2 (K=256, BM=64,BN=128): grid 158x2
    mfma_gemm<1, 64, 128, 256><<<dim3(MP / 64, 2), 256, 0, stream>>>(
        nullptr, hA, B2t, Yrel, hB, brel[1], ss[0], sq[0], bng[0], bnb[0], 256, 256, 128);
    agg_kernel<128><<<2500, 256, 0, stream>>>(Yrel, hB, off, psrc, pew);
    stats_part<128><<<256, 256, 0, stream>>>(hB, pS, pQ);
    stats_reduce<<<128, 256, 0, stream>>>(pS, pQ, ss[1], sq[1], 128);

    // layer 3 (K=128, BM=64,BN=64): grid 158x2
    mfma_gemm<1, 64, 64, 256><<<dim3(MP / 64, 2), 256, 0, stream>>>(
        nullptr, hB, B3t, Yrel, hC, brel[2], ss[1], sq[1], bng[1], bnb[1], 128, 128, 64);
    agg_kernel<64><<<1250, 256, 0, stream>>>(Yrel, hC, off, psrc, pew);
    stats_part<64><<<256, 256, 0, stream>>>(hC, pS, pQ);
    stats_reduce<<<64, 256, 0, stream>>>(pS, pQ, ss[2], sq[2], 64);

    head_kernel<<<2500, 256, 0, stream>>>(hC, ss[2], sq[2], bng[2], bnb[2], wlin, blin, tmp);
    lse_final<<<1, 1024, 0, stream>>>(tmp, out);
}

// Round 9
// 157.406 us; speedup vs baseline: 2.3355x; 1.1210x over previous
//
#include <hip/hip_runtime.h>
#include <math.h>

#define NN 10000
#define EE 160000
#define MP 10112   // 79*128, padded node count
#define EPSBN 1e-5f

typedef __attribute__((ext_vector_type(8))) short short8;
typedef __attribute__((ext_vector_type(4))) short short4v;
typedef __attribute__((ext_vector_type(4))) float f32x4;

__device__ __forceinline__ short f2bf(float f) {
    union { float f; unsigned u; } v; v.f = f;
    unsigned r = v.u + 0x7FFF + ((v.u >> 16) & 1);
    return (short)(r >> 16);
}
__device__ __forceinline__ float bf2f(unsigned short u) {
    union { unsigned u; float f; } v; v.u = ((unsigned)u) << 16;
    return v.f;
}
__device__ __forceinline__ void gload16(const short* g, short* l) {
    __builtin_amdgcn_global_load_lds((const __attribute__((address_space(1))) void*)g,
                                     (__attribute__((address_space(3))) void*)l, 16, 0, 0);
}

// ---------------- fused prep: conv_x (blocks 0..2847) + conv_w (2848..3743) + count (3744..4368) ----------------

__global__ __launch_bounds__(256) void prep_kernel(const float* __restrict__ x, short* __restrict__ A,
                                                   const float* __restrict__ w1r, const float* __restrict__ w1o,
                                                   const float* __restrict__ w2r, const float* __restrict__ w2o,
                                                   const float* __restrict__ w3r, const float* __restrict__ w3o,
                                                   short* __restrict__ B1, short* __restrict__ B2, short* __restrict__ B3,
                                                   const int* __restrict__ dst, int* __restrict__ deg) {
    int b = blockIdx.x;
    if (b < 2848) {
        int idx = b * 256 + threadIdx.x;
        if (idx >= MP * 72) return;
        int row = idx / 72;
        int c0 = (idx % 72) * 8;
        short8 s;
        bool gr = (row < NN);
#pragma unroll
        for (int j = 0; j < 8; j++) {
            int c = c0 + j;
            float v = (gr && c < 517) ? x[(size_t)row * 517 + c] : 0.f;
            s[j] = f2bf(v);
        }
        *(short8*)&A[(size_t)row * 576 + c0] = s;
    } else if (b < 3744) {
        int j = b - 2848;
        const float *Wr, *Wo;
        short* Bt;
        int K, Kp, fo, row;
        if (j < 512)      { row = j;       Wr = w1r; Wo = w1o; Bt = B1; K = 517; Kp = 576; fo = 256; }
        else if (j < 768) { row = j - 512; Wr = w2r; Wo = w2o; Bt = B2; K = 256; Kp = 256; fo = 128; }
        else              { row = j - 768; Wr = w3r; Wo = w3o; Bt = B3; K = 128; Kp = 128; fo = 64; }
        const float* W = (row < fo) ? Wr : Wo;
        int col = (row < fo) ? row : row - fo;
        for (int k = threadIdx.x; k < Kp; k += 256) {
            short v = 0;
            if (k < K) v = f2bf(W[(size_t)k * fo + col]);
            Bt[(size_t)row * Kp + k] = v;
        }
    } else {
        int e = (b - 3744) * 256 + threadIdx.x;
        if (e < EE) atomicAdd(&deg[dst[e]], 1);
    }
}

// ---------------- CSR scan + fill ----------------

__global__ __launch_bounds__(1024) void scan_kernel(const int* __restrict__ deg, int* __restrict__ off,
                                                    int* __restrict__ cursor, int n) {
    __shared__ int sm[1024];
    const int C = 10;
    int t = threadIdx.x;
    int base = t * C;
    int loc[C];
    int acc = 0;
#pragma unroll
    for (int i = 0; i < C; i++) {
        int idx = base + i;
        int v = (idx < n) ? deg[idx] : 0;
        loc[i] = acc;
        acc += v;
    }
    sm[t] = acc;
    __syncthreads();
    for (int d = 1; d < 1024; d <<= 1) {
        int v = (t >= d) ? sm[t - d] : 0;
        __syncthreads();
        sm[t] += v;
        __syncthreads();
    }
    int prefix = (t > 0) ? sm[t - 1] : 0;
#pragma unroll
    for (int i = 0; i < C; i++) {
        int idx = base + i;
        if (idx < n) {
            int o = prefix + loc[i];
            off[idx] = o;
            cursor[idx] = o;
        }
    }
    if (t == 1023) off[n] = sm[1023];
}

__global__ void fill_kernel(const int* __restrict__ src, const int* __restrict__ dst,
                            const float* __restrict__ ew, int* __restrict__ cursor,
                            int* __restrict__ psrc, float* __restrict__ pew, int E) {
    int e = blockIdx.x * blockDim.x + threadIdx.x;
    if (e < E) {
        int d = dst[e];
        int slot = atomicAdd(&cursor[d], 1);
        psrc[slot] = src[e];
        pew[slot] = ew[e];
    }
}

// ---------------- MFMA GEMM, double-buffered pipeline ----------------
// MODE 0: A = Abf bf16 [MP,Kp] pre-padded, staged via global_load_lds
// MODE 1: A = Af32 f32 [MP,K], BN(scale/shift from sums)+ReLU fused, reg-staged

template <int MODE, int BM, int BN, int NT>
__global__ __launch_bounds__(NT) void mfma_gemm(const short* __restrict__ Abf,
                                                const float* __restrict__ Af32,
                                                const short* __restrict__ Bt,
                                                short* __restrict__ Yrel,
                                                float* __restrict__ Hroot,
                                                const float* __restrict__ brel,
                                                const float* __restrict__ ssum,
                                                const float* __restrict__ ssumsq,
                                                const float* __restrict__ bng,
                                                const float* __restrict__ bnb,
                                                int K, int Kp, int fo) {
    const int N_REP = BN / 16;
    const int ACH = BM * 8 / NT;
    const int BCH = BN * 8 / NT;
    const int AF4 = BM * 16 / NT;

    __shared__ short Als[2][BM * 64];
    __shared__ short Bls[2][BN * 64];
    __shared__ float scs[256], shs[256];

    int m0 = blockIdx.x * BM;
    int n0 = blockIdx.y * BN;
    int t = threadIdx.x;
    int lane = t & 63;
    int wid = t >> 6;

    if (MODE == 1) {
        for (int f = t; f < K; f += NT) {
            float mean = ssum[f] / (float)NN;
            float var = ssumsq[f] / (float)NN - mean * mean;
            var = fmaxf(var, 0.f);
            float sc = bng[f] * rsqrtf(var + EPSBN);
            scs[f] = sc;
            shs[f] = bnb[f] - mean * sc;
        }
        __syncthreads();
    }

    f32x4 acc[N_REP];
#pragma unroll
    for (int j = 0; j < N_REP; j++) acc[j] = (f32x4){0.f, 0.f, 0.f, 0.f};

    f32x4 ld[AF4 > 0 ? AF4 : 1];

    auto stageB = [&](int buf, int k0) {
#pragma unroll
        for (int i = 0; i < BCH; i++) {
            int idx = i * NT + t;
            int row = idx >> 3;
            int pc = idx & 7;
            gload16(Bt + (size_t)(n0 + row) * Kp + k0 + ((pc ^ (row & 7)) << 3), &Bls[buf][idx << 3]);
        }
    };
    auto stageA0 = [&](int buf, int k0) {
#pragma unroll
        for (int i = 0; i < ACH; i++) {
            int idx = i * NT + t;
            int row = idx >> 3;
            int pc = idx & 7;
            gload16(Abf + (size_t)(m0 + row) * Kp + k0 + ((pc ^ (row & 7)) << 3), &Als[buf][idx << 3]);
        }
    };
    auto loadA1 = [&](int k0) {
#pragma unroll
        for (int i = 0; i < AF4; i++) {
            int idx = i * NT + t;
            int row = idx >> 4;
            int fc = idx & 15;
            ld[i] = *(const f32x4*)(Af32 + (size_t)(m0 + row) * K + k0 + (fc << 2));
        }
    };
    auto writeA1 = [&](int buf, int k0) {
#pragma unroll
        for (int i = 0; i < AF4; i++) {
            int idx = i * NT + t;
            int row = idx >> 4;
            int fc = idx & 15;
            int kb = k0 + (fc << 2);
            short4v s;
#pragma unroll
            for (int j = 0; j < 4; j++) s[j] = f2bf(fmaxf(0.f, ld[i][j] * scs[kb + j] + shs[kb + j]));
            *(short4v*)&Als[buf][row * 64 + (((fc >> 1) ^ (row & 7)) << 3) + ((fc & 1) << 2)] = s;
        }
    };
    auto compute = [&](int buf) {
#pragma unroll
        for (int kk = 0; kk < 2; kk++) {
            int cc = kk * 4 + (lane >> 4);
            short8 af;
            {
                int row = wid * 16 + (lane & 15);
                af = *(const short8*)&Als[buf][(row * 8 + (cc ^ (row & 7))) * 8];
            }
#pragma unroll
            for (int ni = 0; ni < N_REP; ni++) {
                int row = ni * 16 + (lane & 15);
                short8 b8 = *(const short8*)&Bls[buf][(row * 8 + (cc ^ (row & 7))) * 8];
                acc[ni] = __builtin_amdgcn_mfma_f32_16x16x32_bf16(af, b8, acc[ni], 0, 0, 0);
            }
        }
    };

    int nsteps = Kp / 64;
    if (MODE == 0) stageA0(0, 0);
    else { loadA1(0); writeA1(0, 0); }
    stageB(0, 0);
    __syncthreads();

    int cur = 0;
    for (int s = 0; s < nsteps; s++) {
        int k1 = (s + 1) * 64;
        bool nxt = (s + 1 < nsteps);
        if (nxt) {
            if (MODE == 0) stageA0(cur ^ 1, k1);
            else loadA1(k1);
            stageB(cur ^ 1, k1);
        }
        compute(cur);
        if (nxt && MODE == 1) writeA1(cur ^ 1, k1);
        __syncthreads();
        cur ^= 1;
    }

#pragma unroll
    for (int ni = 0; ni < N_REP; ni++) {
        int gn = n0 + ni * 16 + (lane & 15);
        int row0 = m0 + wid * 16 + (lane >> 4) * 4;
        f32x4 v = acc[ni];
        if (gn < fo) {
#pragma unroll
            for (int r = 0; r < 4; r++) Yrel[(size_t)(row0 + r) * fo + gn] = f2bf(v[r]);
        } else {
            float bb = brel[gn - fo];
#pragma unroll
            for (int r = 0; r < 4; r++) Hroot[(size_t)(row0 + r) * fo + (gn - fo)] = v[r] + bb;
        }
    }
}

// ---------------- pure aggregation: hio[n,f] += sum_e w*Yrel[src,f], 4-unrolled ----------------

template <int FO>
__global__ __launch_bounds__(256) void agg_kernel(const short* __restrict__ Yrel,
                                                  float* __restrict__ hio,
                                                  const int* __restrict__ off,
                                                  const int* __restrict__ psrc,
                                                  const float* __restrict__ pew) {
    const int G = FO / 2;
    const int NPB = 256 / G;
    int t = threadIdx.x;
    int g = t / G;
    int tf = t % G;
    int f = tf * 2;
    int n = blockIdx.x * NPB + g;
    if (n >= NN) return;

    float a0 = 0.f, a1 = 0.f, b0 = 0.f, b1 = 0.f;
    int e0 = off[n], e1 = off[n + 1];
    int e = e0;
    for (; e + 3 < e1; e += 4) {
        int s0i = psrc[e], s1i = psrc[e + 1], s2i = psrc[e + 2], s3i = psrc[e + 3];
        float w0 = pew[e], w1 = pew[e + 1], w2 = pew[e + 2], w3 = pew[e + 3];
        unsigned p0 = *(const unsigned*)(Yrel + (size_t)s0i * FO + f);
        unsigned p1 = *(const unsigned*)(Yrel + (size_t)s1i * FO + f);
        unsigned p2 = *(const unsigned*)(Yrel + (size_t)s2i * FO + f);
        unsigned p3 = *(const unsigned*)(Yrel + (size_t)s3i * FO + f);
        a0 += w0 * bf2f((unsigned short)(p0 & 0xffff));
        a1 += w0 * bf2f((unsigned short)(p0 >> 16));
        b0 += w1 * bf2f((unsigned short)(p1 & 0xffff));
        b1 += w1 * bf2f((unsigned short)(p1 >> 16));
        a0 += w2 * bf2f((unsigned short)(p2 & 0xffff));
        a1 += w2 * bf2f((unsigned short)(p2 >> 16));
        b0 += w3 * bf2f((unsigned short)(p3 & 0xffff));
        b1 += w3 * bf2f((unsigned short)(p3 >> 16));
    }
    for (; e < e1; e++) {
        int s0i = psrc[e];
        float w0 = pew[e];
        unsigned p0 = *(const unsigned*)(Yrel + (size_t)s0i * FO + f);
        a0 += w0 * bf2f((unsigned short)(p0 & 0xffff));
        a1 += w0 * bf2f((unsigned short)(p0 >> 16));
    }
    size_t o = (size_t)n * FO + f;
    hio[o]     += a0 + b0;
    hio[o + 1] += a1 + b1;
}

// ---------------- BN stats: 2-stage deterministic reduction ----------------

template <int FO>
__global__ __launch_bounds__(256) void stats_part(const float* __restrict__ hio,
                                                  float* __restrict__ pS,
                                                  float* __restrict__ pQ) {
    const int FG = FO / 4;
    const int ROWL = 256 / FG;
    const int RPB = (NN + 255) / 256;
    __shared__ f32x4 sms[256], smq[256];
    int t = threadIdx.x;
    int fg = t % FG;
    int rl = t / FG;
    int r0 = blockIdx.x * RPB;
    int r1 = r0 + RPB;
    if (r1 > NN) r1 = NN;
    f32x4 s = (f32x4){0.f, 0.f, 0.f, 0.f};
    f32x4 q = (f32x4){0.f, 0.f, 0.f, 0.f};
    for (int r = r0 + rl; r < r1; r += ROWL) {
        f32x4 v = *(const f32x4*)(hio + (size_t)r * FO + fg * 4);
        s += v;
        q += v * v;
    }
    sms[t] = s;
    smq[t] = q;
    __syncthreads();
    if (rl == 0) {
#pragma unroll
        for (int l = 1; l < ROWL; l++) {
            s += sms[l * FG + fg];
            q += smq[l * FG + fg];
        }
        *(f32x4*)(pS + (size_t)blockIdx.x * FO + fg * 4) = s;
        *(f32x4*)(pQ + (size_t)blockIdx.x * FO + fg * 4) = q;
    }
}

__global__ __launch_bounds__(256) void stats_reduce(const float* __restrict__ pS,
                                                    const float* __restrict__ pQ,
                                                    float* __restrict__ ssum,
                                                    float* __restrict__ ssumsq,
                                                    int FO) {
    int f = blockIdx.x;
    int t = threadIdx.x;
    float s = pS[(size_t)t * FO + f];
    float q = pQ[(size_t)t * FO + f];
#pragma unroll
    for (int o = 32; o > 0; o >>= 1) {
        s += __shfl_down(s, o, 64);
        q += __shfl_down(q, o, 64);
    }
    __shared__ float smS[4], smQ[4];
    int lane = t & 63, w = t >> 6;
    if (lane == 0) { smS[w] = s; smQ[w] = q; }
    __syncthreads();
    if (t == 0) {
        ssum[f]   = smS[0] + smS[1] + smS[2] + smS[3];
        ssumsq[f] = smQ[0] + smQ[1] + smQ[2] + smQ[3];
    }
}

// ---------------- head: BN3 + ReLU + dot(wlin) + log_sigmoid ----------------

__global__ void head_kernel(const float* __restrict__ hio,
                            const float* __restrict__ ssum, const float* __restrict__ ssumsq,
                            const float* __restrict__ g3, const float* __restrict__ b3,
                            const float* __restrict__ wlin, const float* __restrict__ blin,
                            float* __restrict__ tmp) {
    int lane = threadIdx.x & 63;
    int wv = threadIdx.x >> 6;
    int n = blockIdx.x * 4 + wv;
    float mean = ssum[lane] / (float)NN;
    float var = ssumsq[lane] / (float)NN - mean * mean;
    var = fmaxf(var, 0.f);
    float sc = g3[lane] * rsqrtf(var + EPSBN);
    float sh = b3[lane] - mean * sc;
    float v = fmaxf(0.f, hio[(size_t)n * 64 + lane] * sc + sh);
    float p = v * wlin[lane];
#pragma unroll
    for (int o = 32; o > 0; o >>= 1) p += __shfl_down(p, o, 64);
    if (lane == 0) {
        float x = p + blin[0];
        float ls = (x >= 0.f) ? (-log1pf(expf(-x))) : (x - log1pf(expf(x)));
        tmp[n] = ls;
    }
}

// ---------------- logsumexp + final subtract (one block) ----------------

__global__ __launch_bounds__(1024) void lse_final(const float* __restrict__ tmp, float* __restrict__ out) {
    __shared__ float sm[1024];
    int t = threadIdx.x;
    float m = -INFINITY;
    for (int i = t; i < NN; i += 1024) m = fmaxf(m, tmp[i]);
    sm[t] = m;
    __syncthreads();
    for (int s = 512; s > 0; s >>= 1) {
        if (t < s) sm[t] = fmaxf(sm[t], sm[t + s]);
        __syncthreads();
    }
    float M = sm[0];
    __syncthreads();
    float acc = 0.f;
    for (int i = t; i < NN; i += 1024) acc += expf(tmp[i] - M);
    sm[t] = acc;
    __syncthreads();
    for (int s = 512; s > 0; s >>= 1) {
        if (t < s) sm[t] += sm[t + s];
        __syncthreads();
    }
    float L = M + logf(sm[0]);
    for (int i = t; i < NN; i += 1024) out[i] = tmp[i] - L;
}

// ---------------- launch ----------------

extern "C" void kernel_launch(void* const* d_in, const int* in_sizes, int n_in,
                              void* d_out, int out_size, void* d_ws, size_t ws_size,
                              hipStream_t stream) {
    const float* x  = (const float*)d_in[0];
    const int* ei   = (const int*)d_in[1];
    const float* ew = (const float*)d_in[2];
    const int* src = ei;
    const int* dst = ei + EE;

    const float* wrel[3]  = { (const float*)d_in[3],  (const float*)d_in[8],  (const float*)d_in[13] };
    const float* brel[3]  = { (const float*)d_in[4],  (const float*)d_in[9],  (const float*)d_in[14] };
    const float* wroot[3] = { (const float*)d_in[5],  (const float*)d_in[10], (const float*)d_in[15] };
    const float* bng[3]   = { (const float*)d_in[6],  (const float*)d_in[11], (const float*)d_in[16] };
    const float* bnb[3]   = { (const float*)d_in[7],  (const float*)d_in[12], (const float*)d_in[17] };
    const float* wlin = (const float*)d_in[18];
    const float* blin = (const float*)d_in[19];
    float* out = (float*)d_out;

    char* p = (char*)d_ws;
    auto alloc = [&](size_t bytes) { char* r = p; p += (bytes + 255) & ~(size_t)255; return r; };

    int*   deg     = (int*)alloc(NN * 4);           // memset region start
    float* ssumAll = (float*)alloc(1536 * 4);
    int*   off     = (int*)alloc((NN + 4) * 4);
    int*   cursor  = (int*)alloc(NN * 4);
    int*   psrc    = (int*)alloc(EE * 4);
    float* pew     = (float*)alloc(EE * 4);
    short* A1      = (short*)alloc((size_t)MP * 576 * 2);
    short* B1t     = (short*)alloc((size_t)512 * 576 * 2);
    short* B2t     = (short*)alloc((size_t)256 * 256 * 2);
    short* B3t     = (short*)alloc((size_t)128 * 128 * 2);
    short* Yrel    = (short*)alloc((size_t)MP * 256 * 2);
    float* hA      = (float*)alloc((size_t)MP * 256 * 4);
    float* hB      = (float*)alloc((size_t)MP * 128 * 4);
    float* hC      = (float*)alloc((size_t)MP * 64 * 4);
    float* tmp     = (float*)alloc(NN * 4);
    float* pS      = (float*)alloc((size_t)256 * 256 * 4);
    float* pQ      = (float*)alloc((size_t)256 * 256 * 4);

    float* ss[3]  = { ssumAll,       ssumAll + 512,  ssumAll + 1024 };
    float* sq[3]  = { ssumAll + 256, ssumAll + 768,  ssumAll + 1280 };

    hipMemsetAsync(deg, 0, (size_t)((char*)(ssumAll + 1536) - (char*)deg), stream);

    prep_kernel<<<4369, 256, 0, stream>>>(x, A1,
                                          wrel[0], wroot[0], wrel[1], wroot[1], wrel[2], wroot[2],
                                          B1t, B2t, B3t, dst, deg);
    scan_kernel<<<1, 1024, 0, stream>>>(deg, off, cursor, NN);
    fill_kernel<<<(EE + 255) / 256, 256, 0, stream>>>(src, dst, ew, cursor, psrc, pew, EE);

    // layer 1 (K=576, BM=64,BN=128): grid 158x4 = 632 blocks
    mfma_gemm<0, 64, 128, 256><<<dim3(MP / 64, 4), 256, 0, stream>>>(
        A1, nullptr, B1t, Yrel, hA, brel[0], nullptr, nullptr, nullptr, nullptr, 576, 576, 256);
    agg_kernel<256><<<5000, 256, 0, stream>>>(Yrel, hA, off, psrc, pew);
    stats_part<256><<<256, 256, 0, stream>>>(hA, pS, pQ);
    stats_reduce<<<256, 256, 0, stream>>>(pS, pQ, ss[0], sq[0], 256);

    // layer 2 (K=256, BM=64,BN=128): grid 158x2
    mfma_gemm<1, 64, 128, 256><<<dim3(MP / 64, 2), 256, 0, stream>>>(
        nullptr, hA, B2t, Yrel, hB, brel[1], ss[0], sq[0], bng[0], bnb[0], 256, 256, 128);
    agg_kernel<128><<<2500, 256, 0, stream>>>(Yrel, hB, off, psrc, pew);
    stats_part<128><<<256, 256, 0, stream>>>(hB, pS, pQ);
    stats_reduce<<<128, 256, 0, stream>>>(pS, pQ, ss[1], sq[1], 128);

    // layer 3 (K=128, BM=64,BN=64): grid 158x2
    mfma_gemm<1, 64, 64, 256><<<dim3(MP / 64, 2), 256, 0, stream>>>(
        nullptr, hB, B3t, Yrel, hC, brel[2], ss[1], sq[1], bng[1], bnb[1], 128, 128, 64);
    agg_kernel<64><<<1250, 256, 0, stream>>>(Yrel, hC, off, psrc, pew);
    stats_part<64><<<256, 256, 0, stream>>>(hC, pS, pQ);
    stats_reduce<<<64, 256, 0, stream>>>(pS, pQ, ss[2], sq[2], 64);

    head_kernel<<<2500, 256, 0, stream>>>(hC, ss[2], sq[2], bng[2], bnb[2], wlin, blin, tmp);
    lse_final<<<1, 1024, 0, stream>>>(tmp, out);
}